// Round 5
// baseline (232.207 us; speedup 1.0000x reference)
//
#include <hip/hip_runtime.h>
#include <hip/hip_bf16.h>
#include <math.h>

typedef __attribute__((ext_vector_type(8))) __bf16 bf16x8;
typedef __attribute__((ext_vector_type(4))) __bf16 bf16x4;
typedef __attribute__((ext_vector_type(4))) float f32x4;

#define B_ 4
#define T_ 2048
#define C_ 1024
#define H_ 16
#define D_ 64
#define M_TOT (B_*T_)

static __device__ __forceinline__ f32x4 mfma_bf16(bf16x8 a, bf16x8 b, f32x4 c) {
  return __builtin_amdgcn_mfma_f32_16x16x32_bf16(a, b, c, 0, 0, 0);
}

static __device__ __forceinline__ void gload_lds16(const void* g, void* l) {
  __builtin_amdgcn_global_load_lds((const __attribute__((address_space(1))) void*)g,
                                   (__attribute__((address_space(3))) void*)l, 16, 0, 0);
}

// ---------------- converts ----------------

__global__ void f32_to_bf16_k(const float* __restrict__ in, __bf16* __restrict__ out, int n4) {
  int i = blockIdx.x * blockDim.x + threadIdx.x;
  if (i < n4) {
    float4 v = ((const float4*)in)[i];
    bf16x4 o = { (__bf16)v.x, (__bf16)v.y, (__bf16)v.z, (__bf16)v.w };
    *(bf16x4*)(out + (size_t)i*4) = o;
  }
}

// out[n][k] = in[k][n], out bf16 (N x K), in fp32 (K x N)
__global__ void transpose_to_bf16(const float* __restrict__ in, __bf16* __restrict__ out, int K, int N) {
  __shared__ float tile[32][33];
  int n0 = blockIdx.x * 32, k0 = blockIdx.y * 32;
  int tx = threadIdx.x & 31, ty = threadIdx.x >> 5;
  #pragma unroll
  for (int r = ty; r < 32; r += 8) tile[r][tx] = in[(size_t)(k0 + r)*N + n0 + tx];
  __syncthreads();
  #pragma unroll
  for (int r = ty; r < 32; r += 8) out[(size_t)(n0 + r)*K + k0 + tx] = (__bf16)tile[tx][r];
}

__global__ void rope_tables_k(float* __restrict__ cosT, float* __restrict__ sinT) {
  int idx = blockIdx.x * 256 + threadIdx.x;   // T_*32 total
  int t = idx >> 5, d = idx & 31;
  float inv = powf(10000.0f, -((float)(2*d)) / 64.0f);
  float ang = (float)t * inv;
  cosT[idx] = cosf(ang);
  sinT[idx] = sinf(ang);
}

// V [bh][t][d] -> Vt [bh][d][t]
__global__ void __launch_bounds__(256)
vtrans_k(const __bf16* __restrict__ v, __bf16* __restrict__ vt) {
  __shared__ __bf16 tile[64][72];
  const int tid = threadIdx.x;
  const int bh = blockIdx.y;
  const int t0 = blockIdx.x * 64;
  const __bf16* src = v + ((size_t)bh*T_ + t0)*D_;
  #pragma unroll
  for (int c = 0; c < 2; ++c) {
    int idx = tid + c*256;
    int row = idx >> 3, col8 = (idx & 7) * 8;
    *(bf16x8*)&tile[row][col8] = *(const bf16x8*)(src + row*D_ + col8);
  }
  __syncthreads();
  __bf16* dst = vt + (size_t)bh*D_*T_ + t0;
  #pragma unroll
  for (int c = 0; c < 2; ++c) {
    int idx = tid + c*256;
    int d = idx >> 3, t8 = (idx & 7) * 8;
    bf16x8 ov;
    #pragma unroll
    for (int j = 0; j < 8; ++j) ov[j] = tile[t8 + j][d];
    *(bf16x8*)(dst + (size_t)d*T_ + t8) = ov;
  }
}

// ---------------- QKV GEMM: m97 128x128 structure (clone of gemm_out main loop) ----
// Round-4 PMC on the 256x256 dbuf version: 128KB LDS -> 1 block/CU, grid 384 ->
// 1.5 scheduling rounds on 256 CUs -> 500 TF. This 128x128 single-buffer
// structure (proven 912 TF as gemm_out) gives 32KB LDS, ~3 blocks/CU,
// grid 1536 = 64x24 (2 exact rounds at 3/CU). Epilogue: RoPE + QKV scatter;
// each wave owns one 64-col head-slot.
__global__ void __launch_bounds__(256)
gemm_qkv128(const __bf16* __restrict__ A, const __bf16* __restrict__ Bt,
            __bf16* __restrict__ qout, __bf16* __restrict__ kout, __bf16* __restrict__ vout,
            const float* __restrict__ cosT, const float* __restrict__ sinT)
{
  __shared__ __bf16 lA[128*64];
  __shared__ __bf16 lB[128*64];
  const int tid = threadIdx.x;
  const int lane = tid & 63, wave = tid >> 6;
  const int wr = wave >> 1, wc = wave & 1;
  const int l15 = lane & 15, lhi = lane >> 4;

  const int id = blockIdx.x;                 // 1536 blocks (1536 % 8 == 0)
  const int n8 = gridDim.x >> 3;             // 192
  const int swz = (id & 7) * n8 + (id >> 3);
  const int row0 = (swz & 63) * 128;         // M/128 = 64
  const int col0 = (swz >> 6) * 128;         // N/128 = 24

  f32x4 acc[4][4] = {};

  const int stago = wave*1024 + lane*16;
  const size_t arow0 = (size_t)row0 * 2048;  // K=1024, 2048 B/row
  const size_t brow0 = (size_t)col0 * 2048;

  for (int k0 = 0; k0 < 1024; k0 += 64) {
    #pragma unroll
    for (int r = 0; r < 4; ++r) {
      int ob = stago + r*4096;
      int row = ob >> 7;
      int colb = ob & 127;
      gload_lds16((const char*)A + arow0 + (size_t)row*2048 + (size_t)(k0*2 + colb),
                  (char*)lA + ob);
      gload_lds16((const char*)Bt + brow0 + (size_t)row*2048 + (size_t)(k0*2 + colb),
                  (char*)lB + ob);
    }
    __syncthreads();
    #pragma unroll
    for (int kk = 0; kk < 64; kk += 32) {
      bf16x8 af[4], bfr[4];
      #pragma unroll
      for (int m = 0; m < 4; ++m)
        af[m] = *(const bf16x8*)&lA[(wr*64 + m*16 + l15)*64 + kk + lhi*8];
      #pragma unroll
      for (int n = 0; n < 4; ++n)
        bfr[n] = *(const bf16x8*)&lB[(wc*64 + n*16 + l15)*64 + kk + lhi*8];
      #pragma unroll
      for (int m = 0; m < 4; ++m)
        #pragma unroll
        for (int n = 0; n < 4; ++n)
          acc[m][n] = mfma_bf16(af[m], bfr[n], acc[m][n]);
    }
    __syncthreads();
  }

  // epilogue: RoPE on q,k; scatter to (B,H,T,D); q pre-scaled by 0.125*log2e
  const int slot = (col0 >> 6) + wc;         // 0..47
  const int which = slot >> 4;               // 0=q 1=k 2=v
  const int h = slot & 15;
  const float fsc = (which == 0) ? 0.18033688011112042f : 1.0f;
  #pragma unroll
  for (int m = 0; m < 4; ++m) {
    #pragma unroll
    for (int r = 0; r < 4; ++r) {
      const int grow = row0 + wr*64 + m*16 + lhi*4 + r;
      const int b = grow >> 11, t = grow & 2047;
      const size_t obase = ((size_t)(b*H_ + h)*T_ + t)*D_;
      if (which == 2) {
        #pragma unroll
        for (int n = 0; n < 4; ++n)
          vout[obase + n*16 + l15] = (__bf16)acc[m][n][r];
      } else {
        __bf16* dst = (which == 0) ? qout : kout;
        #pragma unroll
        for (int n = 0; n < 2; ++n) {
          const int d1 = n*16 + l15;            // [0,32)
          const float c = cosT[t*32 + d1];
          const float s = sinT[t*32 + d1];
          const float x1 = acc[m][n][r];
          const float x2 = acc[m][n+2][r];
          dst[obase + d1]      = (__bf16)((x1*c - x2*s) * fsc);
          dst[obase + d1 + 32] = (__bf16)((x1*s + x2*c) * fsc);
        }
      }
    }
  }
}

// ---------------- out-proj GEMM (m97 structure: 128x128 tile, BK=64, 4 waves) -------
#define BM 128
#define BN 128
#define BK 64

__global__ void __launch_bounds__(256)
gemm_out(const __bf16* __restrict__ A, const __bf16* __restrict__ Bt, int K,
         float* __restrict__ fout, const float* __restrict__ bias)
{
  __shared__ __bf16 lA[BM*BK];
  __shared__ __bf16 lB[BN*BK];
  const int tid = threadIdx.x;
  const int lane = tid & 63, wave = tid >> 6;
  const int wr = wave >> 1, wc = wave & 1;
  const int l15 = lane & 15, lhi = lane >> 4;

  const int id = blockIdx.x;
  const int n8 = gridDim.x >> 3;
  const int swz = (id & 7) * n8 + (id >> 3);
  const int row0 = (swz & 63) * BM;
  const int col0 = (swz >> 6) * BN;

  f32x4 acc[4][4] = {};

  const int stago = wave*1024 + lane*16;
  const size_t arow0 = (size_t)row0 * (size_t)(K*2);
  const size_t brow0 = (size_t)col0 * (size_t)(K*2);

  for (int k0 = 0; k0 < K; k0 += BK) {
    #pragma unroll
    for (int r = 0; r < 4; ++r) {
      int ob = stago + r*4096;
      int row = ob >> 7;
      int colb = ob & 127;
      gload_lds16((const char*)A + arow0 + (size_t)row*(size_t)(K*2) + (size_t)(k0*2 + colb),
                  (char*)lA + ob);
      gload_lds16((const char*)Bt + brow0 + (size_t)row*(size_t)(K*2) + (size_t)(k0*2 + colb),
                  (char*)lB + ob);
    }
    __syncthreads();
    #pragma unroll
    for (int kk = 0; kk < BK; kk += 32) {
      bf16x8 af[4], bfr[4];
      #pragma unroll
      for (int m = 0; m < 4; ++m)
        af[m] = *(const bf16x8*)&lA[(wr*64 + m*16 + l15)*BK + kk + lhi*8];
      #pragma unroll
      for (int n = 0; n < 4; ++n)
        bfr[n] = *(const bf16x8*)&lB[(wc*64 + n*16 + l15)*BK + kk + lhi*8];
      #pragma unroll
      for (int m = 0; m < 4; ++m)
        #pragma unroll
        for (int n = 0; n < 4; ++n)
          acc[m][n] = mfma_bf16(af[m], bfr[n], acc[m][n]);
    }
    __syncthreads();
  }

  #pragma unroll
  for (int m = 0; m < 4; ++m) {
    #pragma unroll
    for (int r = 0; r < 4; ++r) {
      const int grow = row0 + wr*64 + m*16 + lhi*4 + r;
      #pragma unroll
      for (int n = 0; n < 4; ++n) {
        const int gcol = col0 + wc*64 + n*16 + l15;
        fout[(size_t)grow*1024 + gcol] = acc[m][n][r] + bias[gcol];
      }
    }
  }
}

// ---------------- flash attention: split-KV + LPT, Q-in-LDS, 3 blocks/CU ----------
#define THR_LOG2 8.0f

// group (blockIdx>>6) -> qblock, split (0/1 = kv half, 2 = direct full range)
static __device__ const char QB_TAB[24] = {15,15,7,14,14,13,13,6,12,12,11,11,5,10,10,9,9,4,8,8,3,2,1,0};
static __device__ const char SP_TAB[24] = { 0, 1,2, 0, 1, 0, 1,2, 0, 1, 0, 1,2, 0, 1,0,1,2,0,1,2,2,2,2};

__global__ void __launch_bounds__(256, 3)
attn_kernel(const __bf16* __restrict__ q, const __bf16* __restrict__ k,
            const __bf16* __restrict__ vt, const int* __restrict__ amask,
            __bf16* __restrict__ aout,
            float* __restrict__ pO, float* __restrict__ pM, float* __restrict__ pL)
{
  __shared__ __attribute__((aligned(16))) __bf16 lK[64*64];    // 8 KB
  __shared__ __attribute__((aligned(16))) __bf16 lVt[64*64];   // 8 KB
  __shared__ __attribute__((aligned(16))) __bf16 lP[4][32*64]; // 16 KB
  __shared__ __attribute__((aligned(16))) __bf16 lQ[128*64];   // 16 KB
  const int tid = threadIdx.x;
  const int lane = tid & 63, wave = tid >> 6;
  const int l15 = lane & 15, lhi = lane >> 4;

  const int g = blockIdx.x >> 6;
  const int bh = blockIdx.x & 63;
  const int qblock = QB_TAB[g];
  const int sp = SP_TAB[g];
  const int kb0   = (sp == 1) ? (qblock + 1) : 0;
  const int kbend = (sp == 0) ? (qblock + 1) : (2*qblock + 2);

  const int b = bh >> 4, h = bh & 15;
  const size_t kvbase = (size_t)bh * T_ * D_;
  const char* kbase  = (const char*)(k + kvbase);
  const char* vtbase = (const char*)(vt + kvbase);
  char* lPw = (char*)lP[wave];

  const int q0w = qblock*128 + wave*32;

  // stage Q tile (128 rows x 128B) once; swizzled like lK
  {
    const char* qgbase = (const char*)(q + kvbase) + (size_t)qblock*128*128;
    #pragma unroll
    for (int c = 0; c < 4; ++c) {
      const int L = tid*16 + c*4096;
      const int row = L >> 7;
      const int sb = (L & 127) ^ ((row & 7) << 4);
      gload_lds16(qgbase + (size_t)row*128 + sb, (char*)lQ + L);
    }
  }

  f32x4 acc_o[2][4] = {};
  f32x4 acc_l[2] = {};
  float m_w = -3e37f;

  for (int kb = kb0; kb < kbend; ++kb) {
    #pragma unroll
    for (int c = 0; c < 2; ++c) {
      const int L = tid*16 + c*4096;
      const int row = L >> 7;
      const int sb  = (L & 127) ^ ((row & 7) << 4);
      gload_lds16(kbase  + (size_t)(kb*64 + row)*128 + sb, (char*)lK + L);
      gload_lds16(vtbase + (size_t)row*(T_*2) + (size_t)kb*128 + sb, (char*)lVt + L);
    }
    __syncthreads();

    if (kb*64 <= q0w + 31) {
      const char* lKc = (const char*)lK;
      const char* lVc = (const char*)lVt;
      const char* lQw = (const char*)lQ + (wave*32)*128;
      asm volatile("" : "+v"(lQw));   // defeat cross-iteration hoist of Q reads

      // Q fragments from LDS (re-read each iteration -> not loop-carried regs)
      bf16x8 aq[2][2];
      #pragma unroll
      for (int m = 0; m < 2; ++m) {
        const int lr = m*16 + l15;
        const int sw = (lr & 7) << 4;
        #pragma unroll
        for (int ks = 0; ks < 2; ++ks)
          aq[m][ks] = *(const bf16x8*)(lQw + lr*128 + ((ks*64 + lhi*16) ^ sw));
      }

      f32x4 sc[2][4] = {};
      __builtin_amdgcn_s_setprio(1);
      #pragma unroll
      for (int n = 0; n < 4; ++n) {
        const int row = n*16 + l15;
        const int sw = (row & 7) << 4;
        #pragma unroll
        for (int ks = 0; ks < 2; ++ks) {
          bf16x8 bk = *(const bf16x8*)(lKc + row*128 + ((ks*64 + lhi*16) ^ sw));
          #pragma unroll
          for (int m = 0; m < 2; ++m)
            sc[m][n] = mfma_bf16(aq[m][ks], bk, sc[m][n]);
        }
      }
      __builtin_amdgcn_s_setprio(0);

      if (kb*64 + 63 > q0w) {
        #pragma unroll
        for (int m = 0; m < 2; ++m)
          #pragma unroll
          for (int r = 0; r < 4; ++r) {
            const int tq = q0w + m*16 + lhi*4 + r;
            #pragma unroll
            for (int n = 0; n < 4; ++n)
              if (kb*64 + n*16 + l15 > tq) sc[m][n][r] = -3e37f;
          }
      }

      f32x4 vm = sc[0][0];
      #pragma unroll
      for (int m = 0; m < 2; ++m)
        #pragma unroll
        for (int n = 0; n < 4; ++n) {
          if (m == 0 && n == 0) continue;
          #pragma unroll
          for (int r = 0; r < 4; ++r) vm[r] = fmaxf(vm[r], sc[m][n][r]);
        }
      float tmax = fmaxf(fmaxf(vm[0], vm[1]), fmaxf(vm[2], vm[3]));
      #pragma unroll
      for (int off = 1; off < 64; off <<= 1)
        tmax = fmaxf(tmax, __shfl_xor(tmax, off));

      if (tmax > m_w + THR_LOG2) {
        const float corr = __builtin_amdgcn_exp2f(m_w - tmax);
        #pragma unroll
        for (int m = 0; m < 2; ++m) {
          #pragma unroll
          for (int c = 0; c < 4; ++c) acc_o[m][c] *= corr;
          acc_l[m] *= corr;
        }
        m_w = tmax;
      }

      float mk[4];
      #pragma unroll
      for (int n = 0; n < 4; ++n)
        mk[n] = (amask[b*T_ + kb*64 + n*16 + l15] != 0) ? m_w : 3e37f;

      #pragma unroll
      for (int m = 0; m < 2; ++m)
        #pragma unroll
        for (int r = 0; r < 4; ++r) {
          const int row = m*16 + lhi*4 + r;
          const int sw = (row & 7) << 4;
          #pragma unroll
          for (int n = 0; n < 4; ++n) {
            const float p = __builtin_amdgcn_exp2f(sc[m][n][r] - mk[n]);
            *(__bf16*)(lPw + row*128 + ((((n*16 + l15)*2)) ^ sw)) = (__bf16)p;
          }
        }

      bf16x8 pa[2][2];
      #pragma unroll
      for (int m = 0; m < 2; ++m) {
        const int row = m*16 + l15;
        const int sw = (row & 7) << 4;
        #pragma unroll
        for (int ks = 0; ks < 2; ++ks)
          pa[m][ks] = *(const bf16x8*)(lPw + row*128 + ((ks*64 + lhi*16) ^ sw));
      }

      __builtin_amdgcn_s_setprio(1);
      const __bf16 one = (__bf16)1.0f;
      const bf16x8 vone = {one, one, one, one, one, one, one, one};
      #pragma unroll
      for (int m = 0; m < 2; ++m)
        #pragma unroll
        for (int ks = 0; ks < 2; ++ks)
          acc_l[m] = mfma_bf16(pa[m][ks], vone, acc_l[m]);

      #pragma unroll
      for (int c = 0; c < 4; ++c) {
        const int row = c*16 + l15;
        const int sw = (row & 7) << 4;
        #pragma unroll
        for (int ks = 0; ks < 2; ++ks) {
          bf16x8 bv = *(const bf16x8*)(lVc + row*128 + ((ks*64 + lhi*16) ^ sw));
          #pragma unroll
          for (int m = 0; m < 2; ++m)
            acc_o[m][c] = mfma_bf16(pa[m][ks], bv, acc_o[m][c]);
        }
      }
      __builtin_amdgcn_s_setprio(0);
    }
    __syncthreads();
  }

  if (sp == 2) {
    // direct: normalize and write
    #pragma unroll
    for (int m = 0; m < 2; ++m)
      #pragma unroll
      for (int r = 0; r < 4; ++r) {
        const int tq = q0w + m*16 + lhi*4 + r;
        const float invl = 1.0f / acc_l[m][r];
        const size_t obase = ((size_t)b*T_ + tq)*C_ + h*D_;
        #pragma unroll
        for (int c = 0; c < 4; ++c)
          aout[obase + c*16 + l15] = (__bf16)(acc_o[m][c][r] * invl);
      }
  } else {
    // partial: unnormalized O (f32) + per-row m, l
    const int pidx = ((qblock - 8)*2 + sp)*64 + bh;
    float* po = pO + (size_t)pidx*128*64;
    float* pm = pM + pidx*128;
    float* pl = pL + pidx*128;
    #pragma unroll
    for (int m = 0; m < 2; ++m)
      #pragma unroll
      for (int r = 0; r < 4; ++r) {
        const int rw = wave*32 + m*16 + lhi*4 + r;
        if (l15 == 0) { pm[rw] = m_w; pl[rw] = acc_l[m][r]; }
        #pragma unroll
        for (int c = 0; c < 4; ++c)
          po[(size_t)rw*64 + c*16 + l15] = acc_o[m][c][r];
      }
  }
}

// merge the two kv-split partials for qblock in [8,16)
__global__ void __launch_bounds__(256)
attn_combine(const float* __restrict__ pO, const float* __restrict__ pM,
             const float* __restrict__ pL, __bf16* __restrict__ aout)
{
  const int g = blockIdx.x;            // 512: qb8*64 + bh
  const int qb8 = g >> 6, bh = g & 63;
  const int p0 = (qb8*2)*64 + bh, p1 = (qb8*2 + 1)*64 + bh;
  const int row = threadIdx.x >> 1, ch = threadIdx.x & 1;
  const float m0 = pM[p0*128 + row], m1 = pM[p1*128 + row];
  const float l0 = pL[p0*128 + row], l1 = pL[p1*128 + row];
  const float M = fmaxf(m0, m1);
  const float w0 = __builtin_amdgcn_exp2f(m0 - M);
  const float w1 = __builtin_amdgcn_exp2f(m1 - M);
  const float inv = 1.0f / (l0*w0 + l1*w1);
  const int b = bh >> 4, h = bh & 15;
  const int t = (qb8 + 8)*128 + row;
  const float* o0 = pO + ((size_t)p0*128 + row)*64 + ch*32;
  const float* o1 = pO + ((size_t)p1*128 + row)*64 + ch*32;
  __bf16* dst = aout + ((size_t)b*T_ + t)*C_ + h*D_ + ch*32;
  #pragma unroll
  for (int j = 0; j < 32; j += 4) {
    float4 a = *(const float4*)(o0 + j);
    float4 c = *(const float4*)(o1 + j);
    bf16x4 rr;
    rr[0] = (__bf16)((a.x*w0 + c.x*w1) * inv);
    rr[1] = (__bf16)((a.y*w0 + c.y*w1) * inv);
    rr[2] = (__bf16)((a.z*w0 + c.z*w1) * inv);
    rr[3] = (__bf16)((a.w*w0 + c.w*w1) * inv);
    *(bf16x4*)(dst + j) = rr;
  }
}

// ---------------- launch ----------------

extern "C" void kernel_launch(void* const* d_in, const int* in_sizes, int n_in,
                              void* d_out, int out_size, void* d_ws, size_t ws_size,
                              hipStream_t stream)
{
  const float* x     = (const float*)d_in[0];
  const int*   amask = (const int*)d_in[1];
  const float* Wqkv  = (const float*)d_in[2];
  const float* Wout  = (const float*)d_in[3];
  const float* bout  = (const float*)d_in[4];
  float* out = (float*)d_out;

  char* w = (char*)d_ws;
  __bf16* xb    = (__bf16*)w;  w += (size_t)M_TOT*C_*2;       // 16 MB (reused as vtb after QKV GEMM)
  __bf16* wqkvT = (__bf16*)w;  w += (size_t)3072*1024*2;      // 6 MB
  __bf16* woutT = (__bf16*)w;  w += (size_t)1024*1024*2;      // 2 MB
  __bf16* qb    = (__bf16*)w;  w += (size_t)B_*H_*T_*D_*2;    // 16 MB
  __bf16* kb    = (__bf16*)w;  w += (size_t)B_*H_*T_*D_*2;    // 16 MB
  __bf16* vb    = (__bf16*)w;  w += (size_t)B_*H_*T_*D_*2;    // 16 MB
  __bf16* aob   = (__bf16*)w;  w += (size_t)M_TOT*C_*2;       // 16 MB
  float*  cosT  = (float*)w;   w += (size_t)T_*32*4;
  float*  sinT  = (float*)w;   w += (size_t)T_*32*4;
  float*  pO    = (float*)w;   w += (size_t)1024*128*64*4;    // 33.5 MB split partials
  float*  pM    = (float*)w;   w += (size_t)1024*128*4;
  float*  pL    = (float*)w;   w += (size_t)1024*128*4;
  __bf16* vtb   = xb;   // xb dead after QKV GEMM; alias for V^T

  f32_to_bf16_k<<<(M_TOT*C_/4 + 255)/256, 256, 0, stream>>>(x, xb, M_TOT*C_/4);
  transpose_to_bf16<<<dim3(96, 32), 256, 0, stream>>>(Wqkv, wqkvT, 1024, 3072);
  transpose_to_bf16<<<dim3(32, 32), 256, 0, stream>>>(Wout, woutT, 1024, 1024);
  rope_tables_k<<<(T_*32)/256, 256, 0, stream>>>(cosT, sinT);

  gemm_qkv128<<<dim3(1536), 256, 0, stream>>>(xb, wqkvT, qb, kb, vb, cosT, sinT);

  vtrans_k<<<dim3(T_/64, B_*H_), 256, 0, stream>>>(vb, vtb);

  attn_kernel<<<dim3(1536), 256, 0, stream>>>(qb, kb, vtb, amask, aob, pO, pM, pL);
  attn_combine<<<dim3(512), 256, 0, stream>>>(pO, pM, pL, aob);

  gemm_out<<<dim3(64*8), 256, 0, stream>>>(
      aob, woutT, 1024, out, bout);
}

// Round 6
// 223.420 us; speedup vs baseline: 1.0393x; 1.0393x over previous
//
#include <hip/hip_runtime.h>
#include <hip/hip_bf16.h>
#include <math.h>

typedef __attribute__((ext_vector_type(8))) __bf16 bf16x8;
typedef __attribute__((ext_vector_type(4))) __bf16 bf16x4;
typedef __attribute__((ext_vector_type(4))) float f32x4;

#define B_ 4
#define T_ 2048
#define C_ 1024
#define H_ 16
#define D_ 64
#define M_TOT (B_*T_)

static __device__ __forceinline__ f32x4 mfma_bf16(bf16x8 a, bf16x8 b, f32x4 c) {
  return __builtin_amdgcn_mfma_f32_16x16x32_bf16(a, b, c, 0, 0, 0);
}

static __device__ __forceinline__ void gload_lds16(const void* g, void* l) {
  __builtin_amdgcn_global_load_lds((const __attribute__((address_space(1))) void*)g,
                                   (__attribute__((address_space(3))) void*)l, 16, 0, 0);
}

// ---------------- converts ----------------

__global__ void f32_to_bf16_k(const float* __restrict__ in, __bf16* __restrict__ out, int n4) {
  int i = blockIdx.x * blockDim.x + threadIdx.x;
  if (i < n4) {
    float4 v = ((const float4*)in)[i];
    bf16x4 o = { (__bf16)v.x, (__bf16)v.y, (__bf16)v.z, (__bf16)v.w };
    *(bf16x4*)(out + (size_t)i*4) = o;
  }
}

// out[n][k] = in[k][n], out bf16 (N x K), in fp32 (K x N)
__global__ void transpose_to_bf16(const float* __restrict__ in, __bf16* __restrict__ out, int K, int N) {
  __shared__ float tile[32][33];
  int n0 = blockIdx.x * 32, k0 = blockIdx.y * 32;
  int tx = threadIdx.x & 31, ty = threadIdx.x >> 5;
  #pragma unroll
  for (int r = ty; r < 32; r += 8) tile[r][tx] = in[(size_t)(k0 + r)*N + n0 + tx];
  __syncthreads();
  #pragma unroll
  for (int r = ty; r < 32; r += 8) out[(size_t)(n0 + r)*K + k0 + tx] = (__bf16)tile[tx][r];
}

__global__ void rope_tables_k(float* __restrict__ cosT, float* __restrict__ sinT) {
  int idx = blockIdx.x * 256 + threadIdx.x;   // T_*32 total
  int t = idx >> 5, d = idx & 31;
  float inv = powf(10000.0f, -((float)(2*d)) / 64.0f);
  float ang = (float)t * inv;
  cosT[idx] = cosf(ang);
  sinT[idx] = sinf(ang);
}

// V [bh][t][d] -> Vt [bh][d][t]
__global__ void __launch_bounds__(256)
vtrans_k(const __bf16* __restrict__ v, __bf16* __restrict__ vt) {
  __shared__ __bf16 tile[64][72];
  const int tid = threadIdx.x;
  const int bh = blockIdx.y;
  const int t0 = blockIdx.x * 64;
  const __bf16* src = v + ((size_t)bh*T_ + t0)*D_;
  #pragma unroll
  for (int c = 0; c < 2; ++c) {
    int idx = tid + c*256;
    int row = idx >> 3, col8 = (idx & 7) * 8;
    *(bf16x8*)&tile[row][col8] = *(const bf16x8*)(src + row*D_ + col8);
  }
  __syncthreads();
  __bf16* dst = vt + (size_t)bh*D_*T_ + t0;
  #pragma unroll
  for (int c = 0; c < 2; ++c) {
    int idx = tid + c*256;
    int d = idx >> 3, t8 = (idx & 7) * 8;
    bf16x8 ov;
    #pragma unroll
    for (int j = 0; j < 8; ++j) ov[j] = tile[t8 + j][d];
    *(bf16x8*)(dst + (size_t)d*T_ + t8) = ov;
  }
}

// ---------------- pipelined GEMM: 128x256 tile, BK=64, 8 waves, 3 buffers,
// depth-2 prefetch with COUNTED vmcnt + raw s_barrier (T3+T4 mechanism).
// Per K-tile: 6 gload_lds/thread (2 A + 4 B). Steady state keeps one full
// K-tile (6 loads) in flight across the barrier -> vmcnt(6), never 0 until
// the tail. Buffer safety: reads of buf[cur] finish before each wave's MFMA
// (compiler lgkm waits), hence before the next barrier; restage of that
// buffer is issued only after that barrier. LDS 144 KB -> 1 block/CU.
// Addressing/swizzle/epilogues copied from the round-4/5 verified kernels.

__global__ void __launch_bounds__(512, 2)
gemm_qkv_p(const __bf16* __restrict__ A, const __bf16* __restrict__ Bt,
           __bf16* __restrict__ qout, __bf16* __restrict__ kout, __bf16* __restrict__ vout,
           const float* __restrict__ cosT, const float* __restrict__ sinT)
{
  __shared__ __attribute__((aligned(16))) __bf16 lA[3][128*64];   // 48 KB
  __shared__ __attribute__((aligned(16))) __bf16 lB[3][256*64];   // 96 KB
  const int tid = threadIdx.x;
  const int lane = tid & 63, wave = tid >> 6;
  const int wr = wave >> 2, wc = wave & 3;       // 2M x 4N wave grid
  const int l15 = lane & 15, lhi = lane >> 4;

  const int id = blockIdx.x;                 // 768 blocks (768 % 8 == 0)
  const int n8 = gridDim.x >> 3;             // 96
  const int swz = (id & 7) * n8 + (id >> 3);
  const int row0 = (swz & 63) * 128;         // M/128 = 64
  const int col0 = (swz >> 6) * 256;         // N/256 = 12

  f32x4 acc[4][4] = {};

  const char* Abase = (const char*)A + (size_t)row0 * 2048;   // K=1024, 2048 B/row
  const char* Bbase = (const char*)Bt + (size_t)col0 * 2048;

  auto STAGE = [&](int kt, int s) {
    #pragma unroll
    for (int c = 0; c < 2; ++c) {            // A: 128 rows x 128 B = 16 KB
      const int L = tid*16 + c*8192;
      const int row = L >> 7, colb = L & 127;
      const int sb = colb ^ ((row & 7) << 4);   // inverse swizzle on global source
      gload_lds16(Abase + (size_t)row*2048 + kt*128 + sb, (char*)lA[s] + L);
    }
    #pragma unroll
    for (int c = 0; c < 4; ++c) {            // B: 256 rows x 128 B = 32 KB
      const int L = tid*16 + c*8192;
      const int row = L >> 7, colb = L & 127;
      const int sb = colb ^ ((row & 7) << 4);
      gload_lds16(Bbase + (size_t)row*2048 + kt*128 + sb, (char*)lB[s] + L);
    }
  };

  STAGE(0, 0);
  STAGE(1, 1);
  int cur = 0;
  for (int kt = 0; kt < 16; ++kt) {
    // drain tile kt's 6 loads; keep tile kt+1's 6 in flight (tail: drain all)
    if (kt < 15) asm volatile("s_waitcnt vmcnt(6)" ::: "memory");
    else         asm volatile("s_waitcnt vmcnt(0)" ::: "memory");
    __builtin_amdgcn_s_barrier();
    if (kt < 14) { int s2 = cur + 2; if (s2 >= 3) s2 -= 3; STAGE(kt + 2, s2); }

    const char* cA = (const char*)lA[cur];
    const char* cB = (const char*)lB[cur];

    bf16x8 bfr[4][2];
    #pragma unroll
    for (int n = 0; n < 4; ++n) {
      const int row = wc*64 + n*16 + l15;
      const int sw = (row & 7) << 4;
      #pragma unroll
      for (int ks = 0; ks < 2; ++ks)
        bfr[n][ks] = *(const bf16x8*)(cB + row*128 + ((ks*64 + lhi*16) ^ sw));
    }
    #pragma unroll
    for (int mp = 0; mp < 2; ++mp) {
      bf16x8 af[2][2];
      #pragma unroll
      for (int mm = 0; mm < 2; ++mm) {
        const int row = wr*64 + (mp*2 + mm)*16 + l15;
        const int sw = (row & 7) << 4;
        #pragma unroll
        for (int ks = 0; ks < 2; ++ks)
          af[mm][ks] = *(const bf16x8*)(cA + row*128 + ((ks*64 + lhi*16) ^ sw));
      }
      __builtin_amdgcn_s_setprio(1);
      #pragma unroll
      for (int mm = 0; mm < 2; ++mm)
        #pragma unroll
        for (int n = 0; n < 4; ++n)
          #pragma unroll
          for (int ks = 0; ks < 2; ++ks)
            acc[mp*2 + mm][n] = mfma_bf16(af[mm][ks], bfr[n][ks], acc[mp*2 + mm][n]);
      __builtin_amdgcn_s_setprio(0);
    }
    cur = (cur == 2) ? 0 : cur + 1;
  }

  // epilogue: RoPE on q,k; scatter to (B,H,T,D); q pre-scaled by 0.125*log2e
  const int slot = (col0 >> 6) + wc;         // 0..47
  const int which = slot >> 4;               // 0=q 1=k 2=v
  const int h = slot & 15;
  const float fsc = (which == 0) ? 0.18033688011112042f : 1.0f;
  #pragma unroll
  for (int m = 0; m < 4; ++m) {
    #pragma unroll
    for (int r = 0; r < 4; ++r) {
      const int grow = row0 + wr*64 + m*16 + lhi*4 + r;
      const int b = grow >> 11, t = grow & 2047;
      const size_t obase = ((size_t)(b*H_ + h)*T_ + t)*D_;
      if (which == 2) {
        #pragma unroll
        for (int n = 0; n < 4; ++n)
          vout[obase + n*16 + l15] = (__bf16)acc[m][n][r];
      } else {
        __bf16* dst = (which == 0) ? qout : kout;
        #pragma unroll
        for (int n = 0; n < 2; ++n) {
          const int d1 = n*16 + l15;            // [0,32)
          const float c = cosT[t*32 + d1];
          const float s = sinT[t*32 + d1];
          const float x1 = acc[m][n][r];
          const float x2 = acc[m][n+2][r];
          dst[obase + d1]      = (__bf16)((x1*c - x2*s) * fsc);
          dst[obase + d1 + 32] = (__bf16)((x1*s + x2*c) * fsc);
        }
      }
    }
  }
}

// out-proj: same pipelined structure, bias+f32 epilogue. Grid 64x4 = 256.
__global__ void __launch_bounds__(512, 2)
gemm_out_p(const __bf16* __restrict__ A, const __bf16* __restrict__ Bt,
           float* __restrict__ fout, const float* __restrict__ bias)
{
  __shared__ __attribute__((aligned(16))) __bf16 lA[3][128*64];
  __shared__ __attribute__((aligned(16))) __bf16 lB[3][256*64];
  const int tid = threadIdx.x;
  const int lane = tid & 63, wave = tid >> 6;
  const int wr = wave >> 2, wc = wave & 3;
  const int l15 = lane & 15, lhi = lane >> 4;

  const int id = blockIdx.x;                 // 256 blocks
  const int n8 = gridDim.x >> 3;             // 32
  const int swz = (id & 7) * n8 + (id >> 3);
  const int row0 = (swz & 63) * 128;         // M/128 = 64
  const int col0 = (swz >> 6) * 256;         // N/256 = 4

  f32x4 acc[4][4] = {};

  const char* Abase = (const char*)A + (size_t)row0 * 2048;
  const char* Bbase = (const char*)Bt + (size_t)col0 * 2048;

  auto STAGE = [&](int kt, int s) {
    #pragma unroll
    for (int c = 0; c < 2; ++c) {
      const int L = tid*16 + c*8192;
      const int row = L >> 7, colb = L & 127;
      const int sb = colb ^ ((row & 7) << 4);
      gload_lds16(Abase + (size_t)row*2048 + kt*128 + sb, (char*)lA[s] + L);
    }
    #pragma unroll
    for (int c = 0; c < 4; ++c) {
      const int L = tid*16 + c*8192;
      const int row = L >> 7, colb = L & 127;
      const int sb = colb ^ ((row & 7) << 4);
      gload_lds16(Bbase + (size_t)row*2048 + kt*128 + sb, (char*)lB[s] + L);
    }
  };

  STAGE(0, 0);
  STAGE(1, 1);
  int cur = 0;
  for (int kt = 0; kt < 16; ++kt) {
    if (kt < 15) asm volatile("s_waitcnt vmcnt(6)" ::: "memory");
    else         asm volatile("s_waitcnt vmcnt(0)" ::: "memory");
    __builtin_amdgcn_s_barrier();
    if (kt < 14) { int s2 = cur + 2; if (s2 >= 3) s2 -= 3; STAGE(kt + 2, s2); }

    const char* cA = (const char*)lA[cur];
    const char* cB = (const char*)lB[cur];

    bf16x8 bfr[4][2];
    #pragma unroll
    for (int n = 0; n < 4; ++n) {
      const int row = wc*64 + n*16 + l15;
      const int sw = (row & 7) << 4;
      #pragma unroll
      for (int ks = 0; ks < 2; ++ks)
        bfr[n][ks] = *(const bf16x8*)(cB + row*128 + ((ks*64 + lhi*16) ^ sw));
    }
    #pragma unroll
    for (int mp = 0; mp < 2; ++mp) {
      bf16x8 af[2][2];
      #pragma unroll
      for (int mm = 0; mm < 2; ++mm) {
        const int row = wr*64 + (mp*2 + mm)*16 + l15;
        const int sw = (row & 7) << 4;
        #pragma unroll
        for (int ks = 0; ks < 2; ++ks)
          af[mm][ks] = *(const bf16x8*)(cA + row*128 + ((ks*64 + lhi*16) ^ sw));
      }
      __builtin_amdgcn_s_setprio(1);
      #pragma unroll
      for (int mm = 0; mm < 2; ++mm)
        #pragma unroll
        for (int n = 0; n < 4; ++n)
          #pragma unroll
          for (int ks = 0; ks < 2; ++ks)
            acc[mp*2 + mm][n] = mfma_bf16(af[mm][ks], bfr[n][ks], acc[mp*2 + mm][n]);
      __builtin_amdgcn_s_setprio(0);
    }
    cur = (cur == 2) ? 0 : cur + 1;
  }

  #pragma unroll
  for (int m = 0; m < 4; ++m) {
    #pragma unroll
    for (int r = 0; r < 4; ++r) {
      const int grow = row0 + wr*64 + m*16 + lhi*4 + r;
      #pragma unroll
      for (int n = 0; n < 4; ++n) {
        const int gcol = col0 + wc*64 + n*16 + l15;
        fout[(size_t)grow*1024 + gcol] = acc[m][n][r] + bias[gcol];
      }
    }
  }
}

// ---------------- flash attention: split-KV + LPT, Q-in-LDS, 3 blocks/CU ----------
#define THR_LOG2 8.0f

// group (blockIdx>>6) -> qblock, split (0/1 = kv half, 2 = direct full range)
static __device__ const char QB_TAB[24] = {15,15,7,14,14,13,13,6,12,12,11,11,5,10,10,9,9,4,8,8,3,2,1,0};
static __device__ const char SP_TAB[24] = { 0, 1,2, 0, 1, 0, 1,2, 0, 1, 0, 1,2, 0, 1,0,1,2,0,1,2,2,2,2};

__global__ void __launch_bounds__(256, 3)
attn_kernel(const __bf16* __restrict__ q, const __bf16* __restrict__ k,
            const __bf16* __restrict__ vt, const int* __restrict__ amask,
            __bf16* __restrict__ aout,
            float* __restrict__ pO, float* __restrict__ pM, float* __restrict__ pL)
{
  __shared__ __attribute__((aligned(16))) __bf16 lK[64*64];    // 8 KB
  __shared__ __attribute__((aligned(16))) __bf16 lVt[64*64];   // 8 KB
  __shared__ __attribute__((aligned(16))) __bf16 lP[4][32*64]; // 16 KB
  __shared__ __attribute__((aligned(16))) __bf16 lQ[128*64];   // 16 KB
  const int tid = threadIdx.x;
  const int lane = tid & 63, wave = tid >> 6;
  const int l15 = lane & 15, lhi = lane >> 4;

  const int g = blockIdx.x >> 6;
  const int bh = blockIdx.x & 63;
  const int qblock = QB_TAB[g];
  const int sp = SP_TAB[g];
  const int kb0   = (sp == 1) ? (qblock + 1) : 0;
  const int kbend = (sp == 0) ? (qblock + 1) : (2*qblock + 2);

  const int b = bh >> 4, h = bh & 15;
  const size_t kvbase = (size_t)bh * T_ * D_;
  const char* kbase  = (const char*)(k + kvbase);
  const char* vtbase = (const char*)(vt + kvbase);
  char* lPw = (char*)lP[wave];

  const int q0w = qblock*128 + wave*32;

  // stage Q tile (128 rows x 128B) once; swizzled like lK
  {
    const char* qgbase = (const char*)(q + kvbase) + (size_t)qblock*128*128;
    #pragma unroll
    for (int c = 0; c < 4; ++c) {
      const int L = tid*16 + c*4096;
      const int row = L >> 7;
      const int sb = (L & 127) ^ ((row & 7) << 4);
      gload_lds16(qgbase + (size_t)row*128 + sb, (char*)lQ + L);
    }
  }

  f32x4 acc_o[2][4] = {};
  f32x4 acc_l[2] = {};
  float m_w = -3e37f;

  for (int kb = kb0; kb < kbend; ++kb) {
    #pragma unroll
    for (int c = 0; c < 2; ++c) {
      const int L = tid*16 + c*4096;
      const int row = L >> 7;
      const int sb  = (L & 127) ^ ((row & 7) << 4);
      gload_lds16(kbase  + (size_t)(kb*64 + row)*128 + sb, (char*)lK + L);
      gload_lds16(vtbase + (size_t)row*(T_*2) + (size_t)kb*128 + sb, (char*)lVt + L);
    }
    __syncthreads();

    if (kb*64 <= q0w + 31) {
      const char* lKc = (const char*)lK;
      const char* lVc = (const char*)lVt;
      const char* lQw = (const char*)lQ + (wave*32)*128;
      asm volatile("" : "+v"(lQw));   // defeat cross-iteration hoist of Q reads

      // Q fragments from LDS (re-read each iteration -> not loop-carried regs)
      bf16x8 aq[2][2];
      #pragma unroll
      for (int m = 0; m < 2; ++m) {
        const int lr = m*16 + l15;
        const int sw = (lr & 7) << 4;
        #pragma unroll
        for (int ks = 0; ks < 2; ++ks)
          aq[m][ks] = *(const bf16x8*)(lQw + lr*128 + ((ks*64 + lhi*16) ^ sw));
      }

      f32x4 sc[2][4] = {};
      __builtin_amdgcn_s_setprio(1);
      #pragma unroll
      for (int n = 0; n < 4; ++n) {
        const int row = n*16 + l15;
        const int sw = (row & 7) << 4;
        #pragma unroll
        for (int ks = 0; ks < 2; ++ks) {
          bf16x8 bk = *(const bf16x8*)(lKc + row*128 + ((ks*64 + lhi*16) ^ sw));
          #pragma unroll
          for (int m = 0; m < 2; ++m)
            sc[m][n] = mfma_bf16(aq[m][ks], bk, sc[m][n]);
        }
      }
      __builtin_amdgcn_s_setprio(0);

      if (kb*64 + 63 > q0w) {
        #pragma unroll
        for (int m = 0; m < 2; ++m)
          #pragma unroll
          for (int r = 0; r < 4; ++r) {
            const int tq = q0w + m*16 + lhi*4 + r;
            #pragma unroll
            for (int n = 0; n < 4; ++n)
              if (kb*64 + n*16 + l15 > tq) sc[m][n][r] = -3e37f;
          }
      }

      f32x4 vm = sc[0][0];
      #pragma unroll
      for (int m = 0; m < 2; ++m)
        #pragma unroll
        for (int n = 0; n < 4; ++n) {
          if (m == 0 && n == 0) continue;
          #pragma unroll
          for (int r = 0; r < 4; ++r) vm[r] = fmaxf(vm[r], sc[m][n][r]);
        }
      float tmax = fmaxf(fmaxf(vm[0], vm[1]), fmaxf(vm[2], vm[3]));
      #pragma unroll
      for (int off = 1; off < 64; off <<= 1)
        tmax = fmaxf(tmax, __shfl_xor(tmax, off));

      if (tmax > m_w + THR_LOG2) {
        const float corr = __builtin_amdgcn_exp2f(m_w - tmax);
        #pragma unroll
        for (int m = 0; m < 2; ++m) {
          #pragma unroll
          for (int c = 0; c < 4; ++c) acc_o[m][c] *= corr;
          acc_l[m] *= corr;
        }
        m_w = tmax;
      }

      float mk[4];
      #pragma unroll
      for (int n = 0; n < 4; ++n)
        mk[n] = (amask[b*T_ + kb*64 + n*16 + l15] != 0) ? m_w : 3e37f;

      #pragma unroll
      for (int m = 0; m < 2; ++m)
        #pragma unroll
        for (int r = 0; r < 4; ++r) {
          const int row = m*16 + lhi*4 + r;
          const int sw = (row & 7) << 4;
          #pragma unroll
          for (int n = 0; n < 4; ++n) {
            const float p = __builtin_amdgcn_exp2f(sc[m][n][r] - mk[n]);
            *(__bf16*)(lPw + row*128 + ((((n*16 + l15)*2)) ^ sw)) = (__bf16)p;
          }
        }

      bf16x8 pa[2][2];
      #pragma unroll
      for (int m = 0; m < 2; ++m) {
        const int row = m*16 + l15;
        const int sw = (row & 7) << 4;
        #pragma unroll
        for (int ks = 0; ks < 2; ++ks)
          pa[m][ks] = *(const bf16x8*)(lPw + row*128 + ((ks*64 + lhi*16) ^ sw));
      }

      __builtin_amdgcn_s_setprio(1);
      const __bf16 one = (__bf16)1.0f;
      const bf16x8 vone = {one, one, one, one, one, one, one, one};
      #pragma unroll
      for (int m = 0; m < 2; ++m)
        #pragma unroll
        for (int ks = 0; ks < 2; ++ks)
          acc_l[m] = mfma_bf16(pa[m][ks], vone, acc_l[m]);

      #pragma unroll
      for (int c = 0; c < 4; ++c) {
        const int row = c*16 + l15;
        const int sw = (row & 7) << 4;
        #pragma unroll
        for (int ks = 0; ks < 2; ++ks) {
          bf16x8 bv = *(const bf16x8*)(lVc + row*128 + ((ks*64 + lhi*16) ^ sw));
          #pragma unroll
          for (int m = 0; m < 2; ++m)
            acc_o[m][c] = mfma_bf16(pa[m][ks], bv, acc_o[m][c]);
        }
      }
      __builtin_amdgcn_s_setprio(0);
    }
    __syncthreads();
  }

  if (sp == 2) {
    // direct: normalize and write
    #pragma unroll
    for (int m = 0; m < 2; ++m)
      #pragma unroll
      for (int r = 0; r < 4; ++r) {
        const int tq = q0w + m*16 + lhi*4 + r;
        const float invl = 1.0f / acc_l[m][r];
        const size_t obase = ((size_t)b*T_ + tq)*C_ + h*D_;
        #pragma unroll
        for (int c = 0; c < 4; ++c)
          aout[obase + c*16 + l15] = (__bf16)(acc_o[m][c][r] * invl);
      }
  } else {
    // partial: unnormalized O (f32) + per-row m, l
    const int pidx = ((qblock - 8)*2 + sp)*64 + bh;
    float* po = pO + (size_t)pidx*128*64;
    float* pm = pM + pidx*128;
    float* pl = pL + pidx*128;
    #pragma unroll
    for (int m = 0; m < 2; ++m)
      #pragma unroll
      for (int r = 0; r < 4; ++r) {
        const int rw = wave*32 + m*16 + lhi*4 + r;
        if (l15 == 0) { pm[rw] = m_w; pl[rw] = acc_l[m][r]; }
        #pragma unroll
        for (int c = 0; c < 4; ++c)
          po[(size_t)rw*64 + c*16 + l15] = acc_o[m][c][r];
      }
  }
}

// merge the two kv-split partials for qblock in [8,16)
__global__ void __launch_bounds__(256)
attn_combine(const float* __restrict__ pO, const float* __restrict__ pM,
             const float* __restrict__ pL, __bf16* __restrict__ aout)
{
  const int g = blockIdx.x;            // 512: qb8*64 + bh
  const int qb8 = g >> 6, bh = g & 63;
  const int p0 = (qb8*2)*64 + bh, p1 = (qb8*2 + 1)*64 + bh;
  const int row = threadIdx.x >> 1, ch = threadIdx.x & 1;
  const float m0 = pM[p0*128 + row], m1 = pM[p1*128 + row];
  const float l0 = pL[p0*128 + row], l1 = pL[p1*128 + row];
  const float M = fmaxf(m0, m1);
  const float w0 = __builtin_amdgcn_exp2f(m0 - M);
  const float w1 = __builtin_amdgcn_exp2f(m1 - M);
  const float inv = 1.0f / (l0*w0 + l1*w1);
  const int b = bh >> 4, h = bh & 15;
  const int t = (qb8 + 8)*128 + row;
  const float* o0 = pO + ((size_t)p0*128 + row)*64 + ch*32;
  const float* o1 = pO + ((size_t)p1*128 + row)*64 + ch*32;
  __bf16* dst = aout + ((size_t)b*T_ + t)*C_ + h*D_ + ch*32;
  #pragma unroll
  for (int j = 0; j < 32; j += 4) {
    float4 a = *(const float4*)(o0 + j);
    float4 c = *(const float4*)(o1 + j);
    bf16x4 rr;
    rr[0] = (__bf16)((a.x*w0 + c.x*w1) * inv);
    rr[1] = (__bf16)((a.y*w0 + c.y*w1) * inv);
    rr[2] = (__bf16)((a.z*w0 + c.z*w1) * inv);
    rr[3] = (__bf16)((a.w*w0 + c.w*w1) * inv);
    *(bf16x4*)(dst + j) = rr;
  }
}

// ---------------- launch ----------------

extern "C" void kernel_launch(void* const* d_in, const int* in_sizes, int n_in,
                              void* d_out, int out_size, void* d_ws, size_t ws_size,
                              hipStream_t stream)
{
  const float* x     = (const float*)d_in[0];
  const int*   amask = (const int*)d_in[1];
  const float* Wqkv  = (const float*)d_in[2];
  const float* Wout  = (const float*)d_in[3];
  const float* bout  = (const float*)d_in[4];
  float* out = (float*)d_out;

  char* w = (char*)d_ws;
  __bf16* xb    = (__bf16*)w;  w += (size_t)M_TOT*C_*2;       // 16 MB (reused as vtb after QKV GEMM)
  __bf16* wqkvT = (__bf16*)w;  w += (size_t)3072*1024*2;      // 6 MB
  __bf16* woutT = (__bf16*)w;  w += (size_t)1024*1024*2;      // 2 MB
  __bf16* qb    = (__bf16*)w;  w += (size_t)B_*H_*T_*D_*2;    // 16 MB
  __bf16* kb    = (__bf16*)w;  w += (size_t)B_*H_*T_*D_*2;    // 16 MB
  __bf16* vb    = (__bf16*)w;  w += (size_t)B_*H_*T_*D_*2;    // 16 MB
  __bf16* aob   = (__bf16*)w;  w += (size_t)M_TOT*C_*2;       // 16 MB
  float*  cosT  = (float*)w;   w += (size_t)T_*32*4;
  float*  sinT  = (float*)w;   w += (size_t)T_*32*4;
  float*  pO    = (float*)w;   w += (size_t)1024*128*64*4;    // 33.5 MB split partials
  float*  pM    = (float*)w;   w += (size_t)1024*128*4;
  float*  pL    = (float*)w;   w += (size_t)1024*128*4;
  __bf16* vtb   = xb;   // xb dead after QKV GEMM; alias for V^T

  f32_to_bf16_k<<<(M_TOT*C_/4 + 255)/256, 256, 0, stream>>>(x, xb, M_TOT*C_/4);
  transpose_to_bf16<<<dim3(96, 32), 256, 0, stream>>>(Wqkv, wqkvT, 1024, 3072);
  transpose_to_bf16<<<dim3(32, 32), 256, 0, stream>>>(Wout, woutT, 1024, 1024);
  rope_tables_k<<<(T_*32)/256, 256, 0, stream>>>(cosT, sinT);

  gemm_qkv_p<<<dim3(768), 512, 0, stream>>>(xb, wqkvT, qb, kb, vb, cosT, sinT);

  vtrans_k<<<dim3(T_/64, B_*H_), 256, 0, stream>>>(vb, vtb);

  attn_kernel<<<dim3(1536), 256, 0, stream>>>(qb, kb, vtb, amask, aob, pO, pM, pL);
  attn_combine<<<dim3(512), 256, 0, stream>>>(pO, pM, pL, aob);

  gemm_out_p<<<dim3(256), 512, 0, stream>>>(aob, woutT, out, bout);
}

// Round 7
// 215.652 us; speedup vs baseline: 1.0768x; 1.0360x over previous
//
#include <hip/hip_runtime.h>
#include <hip/hip_bf16.h>
#include <math.h>

typedef __attribute__((ext_vector_type(8))) __bf16 bf16x8;
typedef __attribute__((ext_vector_type(4))) __bf16 bf16x4;
typedef __attribute__((ext_vector_type(4))) float f32x4;

#define B_ 4
#define T_ 2048
#define C_ 1024
#define H_ 16
#define D_ 64
#define M_TOT (B_*T_)

static __device__ __forceinline__ f32x4 mfma_bf16(bf16x8 a, bf16x8 b, f32x4 c) {
  return __builtin_amdgcn_mfma_f32_16x16x32_bf16(a, b, c, 0, 0, 0);
}

static __device__ __forceinline__ void gload_lds16(const void* g, void* l) {
  __builtin_amdgcn_global_load_lds((const __attribute__((address_space(1))) void*)g,
                                   (__attribute__((address_space(3))) void*)l, 16, 0, 0);
}

// ---------------- converts ----------------

__global__ void f32_to_bf16_k(const float* __restrict__ in, __bf16* __restrict__ out, int n4) {
  int i = blockIdx.x * blockDim.x + threadIdx.x;
  if (i < n4) {
    float4 v = ((const float4*)in)[i];
    bf16x4 o = { (__bf16)v.x, (__bf16)v.y, (__bf16)v.z, (__bf16)v.w };
    *(bf16x4*)(out + (size_t)i*4) = o;
  }
}

// out[n][k] = in[k][n], out bf16 (N x K), in fp32 (K x N)
__global__ void transpose_to_bf16(const float* __restrict__ in, __bf16* __restrict__ out, int K, int N) {
  __shared__ float tile[32][33];
  int n0 = blockIdx.x * 32, k0 = blockIdx.y * 32;
  int tx = threadIdx.x & 31, ty = threadIdx.x >> 5;
  #pragma unroll
  for (int r = ty; r < 32; r += 8) tile[r][tx] = in[(size_t)(k0 + r)*N + n0 + tx];
  __syncthreads();
  #pragma unroll
  for (int r = ty; r < 32; r += 8) out[(size_t)(n0 + r)*K + k0 + tx] = (__bf16)tile[tx][r];
}

__global__ void rope_tables_k(float* __restrict__ cosT, float* __restrict__ sinT) {
  int idx = blockIdx.x * 256 + threadIdx.x;   // T_*32 total
  int t = idx >> 5, d = idx & 31;
  float inv = powf(10000.0f, -((float)(2*d)) / 64.0f);
  float ang = (float)t * inv;
  cosT[idx] = cosf(ang);
  sinT[idx] = sinf(ang);
}

// V [bh][t][d] -> Vt [bh][d][t]
__global__ void __launch_bounds__(256)
vtrans_k(const __bf16* __restrict__ v, __bf16* __restrict__ vt) {
  __shared__ __bf16 tile[64][72];
  const int tid = threadIdx.x;
  const int bh = blockIdx.y;
  const int t0 = blockIdx.x * 64;
  const __bf16* src = v + ((size_t)bh*T_ + t0)*D_;
  #pragma unroll
  for (int c = 0; c < 2; ++c) {
    int idx = tid + c*256;
    int row = idx >> 3, col8 = (idx & 7) * 8;
    *(bf16x8*)&tile[row][col8] = *(const bf16x8*)(src + row*D_ + col8);
  }
  __syncthreads();
  __bf16* dst = vt + (size_t)bh*D_*T_ + t0;
  #pragma unroll
  for (int c = 0; c < 2; ++c) {
    int idx = tid + c*256;
    int d = idx >> 3, t8 = (idx & 7) * 8;
    bf16x8 ov;
    #pragma unroll
    for (int j = 0; j < 8; ++j) ov[j] = tile[t8 + j][d];
    *(bf16x8*)(dst + (size_t)d*T_ + t8) = ov;
  }
}

// ---------------- fine-phase pipelined GEMM: 128x256 tile, BK=64, 8 waves -----------
// 4 phases per 2-K-tile iteration (16 MFMA each), fixed buffer roles
// (even tile -> buf0, odd -> buf1), 96 KB LDS, 1 block/CU, grid = exact rounds.
// Phase = { ds_reads; stage-issue; s_barrier; MFMA x16 (setprio); [vmcnt(4)]; s_barrier }.
// vmcnt(4) only before the barriers closing P2/P4 (once per K-tile), never 0 in
// steady state. Hazard ledger:
//  - restage target's last reader finished before the preceding closing barrier
//    (ds_reads are MFMA-consumed before BAR_b);
//  - staged data read only after issuer's vmcnt(4) (outstanding 10 -> 4, draining
//    exactly the 6 loads the next phase reads) + a barrier;
//  - tail peels to vmcnt(0).

#define GEMM_PHASES(N_TILES)                                                     \
  auto RD_BFR = [&](const char* lb, bf16x8 (*bfr)[2]) {                          \
    _Pragma("unroll")                                                            \
    for (int n = 0; n < 4; ++n) {                                                \
      const int row = wc*64 + n*16 + l15;                                        \
      const int sw = (row & 7) << 4;                                             \
      _Pragma("unroll")                                                          \
      for (int ks = 0; ks < 2; ++ks)                                             \
        bfr[n][ks] = *(const bf16x8*)(lb + row*128 + ((ks*64 + lhi*16) ^ sw));   \
    }                                                                            \
  };                                                                             \
  auto RD_AF = [&](const char* la, int mb, bf16x8 (*af)[2]) {                    \
    _Pragma("unroll")                                                            \
    for (int mm = 0; mm < 2; ++mm) {                                             \
      const int row = wr*64 + (mb + mm)*16 + l15;                                \
      const int sw = (row & 7) << 4;                                             \
      _Pragma("unroll")                                                          \
      for (int ks = 0; ks < 2; ++ks)                                             \
        af[mm][ks] = *(const bf16x8*)(la + row*128 + ((ks*64 + lhi*16) ^ sw));   \
    }                                                                            \
  };                                                                             \
  auto MFMA16 = [&](bf16x8 (*af)[2], bf16x8 (*bfr)[2], int mb) {                 \
    __builtin_amdgcn_s_setprio(1);                                               \
    _Pragma("unroll")                                                            \
    for (int mm = 0; mm < 2; ++mm)                                               \
      _Pragma("unroll")                                                          \
      for (int n = 0; n < 4; ++n)                                                \
        _Pragma("unroll")                                                        \
        for (int ks = 0; ks < 2; ++ks)                                           \
          acc[mb + mm][n] = mfma_bf16(af[mm][ks], bfr[n][ks], acc[mb + mm][n]);  \
    __builtin_amdgcn_s_setprio(0);                                               \
  };                                                                             \
  /* prologue: B(0)->lB0, A(0)->lA0, B(1)->lB1; drain B0+A0, keep B1 in flight */\
  STAGE_B(0, (char*)lB[0]); STAGE_A(0, (char*)lA[0]); STAGE_B(1, (char*)lB[1]);  \
  asm volatile("s_waitcnt vmcnt(4)" ::: "memory");                               \
  __builtin_amdgcn_s_barrier();                                                  \
  _Pragma("unroll")                                                              \
  for (int it = 0; it < (N_TILES)/2; ++it) {                                     \
    const int t0 = it*2;                                                         \
    bf16x8 bfr[4][2], af[2][2];                                                  \
    /* P1: tile t0 (buf0), m0,m1; stage A(t0+1)->buf1 */                         \
    RD_BFR((const char*)lB[0], bfr);                                             \
    RD_AF((const char*)lA[0], 0, af);                                            \
    STAGE_A(t0 + 1, (char*)lA[1]);                                               \
    __builtin_amdgcn_s_barrier();                                                \
    MFMA16(af, bfr, 0);                                                          \
    __builtin_amdgcn_s_barrier();                                                \
    /* P2: tile t0, m2,m3; stage B(t0+2)->buf0; vmcnt */                         \
    RD_AF((const char*)lA[0], 2, af);                                            \
    if (t0 + 2 < (N_TILES)) STAGE_B(t0 + 2, (char*)lB[0]);                       \
    __builtin_amdgcn_s_barrier();                                                \
    MFMA16(af, bfr, 2);                                                          \
    if (t0 + 2 < (N_TILES)) asm volatile("s_waitcnt vmcnt(4)" ::: "memory");     \
    else                    asm volatile("s_waitcnt vmcnt(0)" ::: "memory");     \
    __builtin_amdgcn_s_barrier();                                                \
    /* P3: tile t0+1 (buf1), m0,m1; stage A(t0+2)->buf0 */                       \
    RD_BFR((const char*)lB[1], bfr);                                             \
    RD_AF((const char*)lA[1], 0, af);                                            \
    if (t0 + 2 < (N_TILES)) STAGE_A(t0 + 2, (char*)lA[0]);                       \
    __builtin_amdgcn_s_barrier();                                                \
    MFMA16(af, bfr, 0);                                                          \
    __builtin_amdgcn_s_barrier();                                                \
    /* P4: tile t0+1, m2,m3; stage B(t0+3)->buf1; vmcnt */                       \
    RD_AF((const char*)lA[1], 2, af);                                            \
    if (t0 + 3 < (N_TILES)) STAGE_B(t0 + 3, (char*)lB[1]);                       \
    __builtin_amdgcn_s_barrier();                                                \
    MFMA16(af, bfr, 2);                                                          \
    if (it < (N_TILES)/2 - 1) asm volatile("s_waitcnt vmcnt(4)" ::: "memory");   \
    __builtin_amdgcn_s_barrier();                                                \
  }

__global__ void __launch_bounds__(512, 2)
gemm_qkv_p(const __bf16* __restrict__ A, const __bf16* __restrict__ Bt,
           __bf16* __restrict__ qout, __bf16* __restrict__ kout, __bf16* __restrict__ vout,
           const float* __restrict__ cosT, const float* __restrict__ sinT)
{
  __shared__ __attribute__((aligned(16))) __bf16 lA[2][128*64];   // 32 KB
  __shared__ __attribute__((aligned(16))) __bf16 lB[2][256*64];   // 64 KB
  const int tid = threadIdx.x;
  const int lane = tid & 63, wave = tid >> 6;
  const int wr = wave >> 2, wc = wave & 3;       // 2M x 4N wave grid
  const int l15 = lane & 15, lhi = lane >> 4;

  const int id = blockIdx.x;                 // 768 blocks (768 % 8 == 0)
  const int n8 = gridDim.x >> 3;             // 96
  const int swz = (id & 7) * n8 + (id >> 3);
  const int row0 = (swz & 63) * 128;         // M/128 = 64
  const int col0 = (swz >> 6) * 256;         // N/256 = 12

  f32x4 acc[4][4] = {};

  const char* Abase = (const char*)A + (size_t)row0 * 2048;   // K=1024, 2048 B/row
  const char* Bbase = (const char*)Bt + (size_t)col0 * 2048;

  auto STAGE_A = [&](int kt, char* dst) {
    #pragma unroll
    for (int c = 0; c < 2; ++c) {            // A: 128 rows x 128 B = 16 KB
      const int L = tid*16 + c*8192;
      const int row = L >> 7, colb = L & 127;
      const int sb = colb ^ ((row & 7) << 4);   // inverse swizzle on global source
      gload_lds16(Abase + (size_t)row*2048 + kt*128 + sb, dst + L);
    }
  };
  auto STAGE_B = [&](int kt, char* dst) {
    #pragma unroll
    for (int c = 0; c < 4; ++c) {            // B: 256 rows x 128 B = 32 KB
      const int L = tid*16 + c*8192;
      const int row = L >> 7, colb = L & 127;
      const int sb = colb ^ ((row & 7) << 4);
      gload_lds16(Bbase + (size_t)row*2048 + kt*128 + sb, dst + L);
    }
  };

  GEMM_PHASES(16)

  // epilogue: RoPE on q,k; scatter to (B,H,T,D); q pre-scaled by 0.125*log2e
  const int slot = (col0 >> 6) + wc;         // 0..47
  const int which = slot >> 4;               // 0=q 1=k 2=v
  const int h = slot & 15;
  const float fsc = (which == 0) ? 0.18033688011112042f : 1.0f;
  #pragma unroll
  for (int m = 0; m < 4; ++m) {
    #pragma unroll
    for (int r = 0; r < 4; ++r) {
      const int grow = row0 + wr*64 + m*16 + lhi*4 + r;
      const int b = grow >> 11, t = grow & 2047;
      const size_t obase = ((size_t)(b*H_ + h)*T_ + t)*D_;
      if (which == 2) {
        #pragma unroll
        for (int n = 0; n < 4; ++n)
          vout[obase + n*16 + l15] = (__bf16)acc[m][n][r];
      } else {
        __bf16* dst = (which == 0) ? qout : kout;
        #pragma unroll
        for (int n = 0; n < 2; ++n) {
          const int d1 = n*16 + l15;            // [0,32)
          const float c = cosT[t*32 + d1];
          const float s = sinT[t*32 + d1];
          const float x1 = acc[m][n][r];
          const float x2 = acc[m][n+2][r];
          dst[obase + d1]      = (__bf16)((x1*c - x2*s) * fsc);
          dst[obase + d1 + 32] = (__bf16)((x1*s + x2*c) * fsc);
        }
      }
    }
  }
}

// out-proj: same fine-phase structure, bias+f32 epilogue. Grid 64x4 = 256 = 1 round.
__global__ void __launch_bounds__(512, 2)
gemm_out_p(const __bf16* __restrict__ A, const __bf16* __restrict__ Bt,
           float* __restrict__ fout, const float* __restrict__ bias)
{
  __shared__ __attribute__((aligned(16))) __bf16 lA[2][128*64];
  __shared__ __attribute__((aligned(16))) __bf16 lB[2][256*64];
  const int tid = threadIdx.x;
  const int lane = tid & 63, wave = tid >> 6;
  const int wr = wave >> 2, wc = wave & 3;
  const int l15 = lane & 15, lhi = lane >> 4;

  const int id = blockIdx.x;                 // 256 blocks
  const int n8 = gridDim.x >> 3;             // 32
  const int swz = (id & 7) * n8 + (id >> 3);
  const int row0 = (swz & 63) * 128;         // M/128 = 64
  const int col0 = (swz >> 6) * 256;         // N/256 = 4

  f32x4 acc[4][4] = {};

  const char* Abase = (const char*)A + (size_t)row0 * 2048;
  const char* Bbase = (const char*)Bt + (size_t)col0 * 2048;

  auto STAGE_A = [&](int kt, char* dst) {
    #pragma unroll
    for (int c = 0; c < 2; ++c) {
      const int L = tid*16 + c*8192;
      const int row = L >> 7, colb = L & 127;
      const int sb = colb ^ ((row & 7) << 4);
      gload_lds16(Abase + (size_t)row*2048 + kt*128 + sb, dst + L);
    }
  };
  auto STAGE_B = [&](int kt, char* dst) {
    #pragma unroll
    for (int c = 0; c < 4; ++c) {
      const int L = tid*16 + c*8192;
      const int row = L >> 7, colb = L & 127;
      const int sb = colb ^ ((row & 7) << 4);
      gload_lds16(Bbase + (size_t)row*2048 + kt*128 + sb, dst + L);
    }
  };

  GEMM_PHASES(16)

  #pragma unroll
  for (int m = 0; m < 4; ++m) {
    #pragma unroll
    for (int r = 0; r < 4; ++r) {
      const int grow = row0 + wr*64 + m*16 + lhi*4 + r;
      #pragma unroll
      for (int n = 0; n < 4; ++n) {
        const int gcol = col0 + wc*64 + n*16 + l15;
        fout[(size_t)grow*1024 + gcol] = acc[m][n][r] + bias[gcol];
      }
    }
  }
}

// ---------------- flash attention: split-KV + LPT, Q-in-LDS, 3 blocks/CU ----------
#define THR_LOG2 8.0f

// group (blockIdx>>6) -> qblock, split (0/1 = kv half, 2 = direct full range)
static __device__ const char QB_TAB[24] = {15,15,7,14,14,13,13,6,12,12,11,11,5,10,10,9,9,4,8,8,3,2,1,0};
static __device__ const char SP_TAB[24] = { 0, 1,2, 0, 1, 0, 1,2, 0, 1, 0, 1,2, 0, 1,0,1,2,0,1,2,2,2,2};

__global__ void __launch_bounds__(256, 3)
attn_kernel(const __bf16* __restrict__ q, const __bf16* __restrict__ k,
            const __bf16* __restrict__ vt, const int* __restrict__ amask,
            __bf16* __restrict__ aout,
            float* __restrict__ pO, float* __restrict__ pM, float* __restrict__ pL)
{
  __shared__ __attribute__((aligned(16))) __bf16 lK[64*64];    // 8 KB
  __shared__ __attribute__((aligned(16))) __bf16 lVt[64*64];   // 8 KB
  __shared__ __attribute__((aligned(16))) __bf16 lP[4][32*64]; // 16 KB
  __shared__ __attribute__((aligned(16))) __bf16 lQ[128*64];   // 16 KB
  const int tid = threadIdx.x;
  const int lane = tid & 63, wave = tid >> 6;
  const int l15 = lane & 15, lhi = lane >> 4;

  const int g = blockIdx.x >> 6;
  const int bh = blockIdx.x & 63;
  const int qblock = QB_TAB[g];
  const int sp = SP_TAB[g];
  const int kb0   = (sp == 1) ? (qblock + 1) : 0;
  const int kbend = (sp == 0) ? (qblock + 1) : (2*qblock + 2);

  const int b = bh >> 4, h = bh & 15;
  const size_t kvbase = (size_t)bh * T_ * D_;
  const char* kbase  = (const char*)(k + kvbase);
  const char* vtbase = (const char*)(vt + kvbase);
  char* lPw = (char*)lP[wave];

  const int q0w = qblock*128 + wave*32;

  // stage Q tile (128 rows x 128B) once; swizzled like lK
  {
    const char* qgbase = (const char*)(q + kvbase) + (size_t)qblock*128*128;
    #pragma unroll
    for (int c = 0; c < 4; ++c) {
      const int L = tid*16 + c*4096;
      const int row = L >> 7;
      const int sb = (L & 127) ^ ((row & 7) << 4);
      gload_lds16(qgbase + (size_t)row*128 + sb, (char*)lQ + L);
    }
  }

  f32x4 acc_o[2][4] = {};
  f32x4 acc_l[2] = {};
  float m_w = -3e37f;

  for (int kb = kb0; kb < kbend; ++kb) {
    #pragma unroll
    for (int c = 0; c < 2; ++c) {
      const int L = tid*16 + c*4096;
      const int row = L >> 7;
      const int sb  = (L & 127) ^ ((row & 7) << 4);
      gload_lds16(kbase  + (size_t)(kb*64 + row)*128 + sb, (char*)lK + L);
      gload_lds16(vtbase + (size_t)row*(T_*2) + (size_t)kb*128 + sb, (char*)lVt + L);
    }
    __syncthreads();

    if (kb*64 <= q0w + 31) {
      const char* lKc = (const char*)lK;
      const char* lVc = (const char*)lVt;
      const char* lQw = (const char*)lQ + (wave*32)*128;
      asm volatile("" : "+v"(lQw));   // defeat cross-iteration hoist of Q reads

      // Q fragments from LDS (re-read each iteration -> not loop-carried regs)
      bf16x8 aq[2][2];
      #pragma unroll
      for (int m = 0; m < 2; ++m) {
        const int lr = m*16 + l15;
        const int sw = (lr & 7) << 4;
        #pragma unroll
        for (int ks = 0; ks < 2; ++ks)
          aq[m][ks] = *(const bf16x8*)(lQw + lr*128 + ((ks*64 + lhi*16) ^ sw));
      }

      f32x4 sc[2][4] = {};
      __builtin_amdgcn_s_setprio(1);
      #pragma unroll
      for (int n = 0; n < 4; ++n) {
        const int row = n*16 + l15;
        const int sw = (row & 7) << 4;
        #pragma unroll
        for (int ks = 0; ks < 2; ++ks) {
          bf16x8 bk = *(const bf16x8*)(lKc + row*128 + ((ks*64 + lhi*16) ^ sw));
          #pragma unroll
          for (int m = 0; m < 2; ++m)
            sc[m][n] = mfma_bf16(aq[m][ks], bk, sc[m][n]);
        }
      }
      __builtin_amdgcn_s_setprio(0);

      if (kb*64 + 63 > q0w) {
        #pragma unroll
        for (int m = 0; m < 2; ++m)
          #pragma unroll
          for (int r = 0; r < 4; ++r) {
            const int tq = q0w + m*16 + lhi*4 + r;
            #pragma unroll
            for (int n = 0; n < 4; ++n)
              if (kb*64 + n*16 + l15 > tq) sc[m][n][r] = -3e37f;
          }
      }

      f32x4 vm = sc[0][0];
      #pragma unroll
      for (int m = 0; m < 2; ++m)
        #pragma unroll
        for (int n = 0; n < 4; ++n) {
          if (m == 0 && n == 0) continue;
          #pragma unroll
          for (int r = 0; r < 4; ++r) vm[r] = fmaxf(vm[r], sc[m][n][r]);
        }
      float tmax = fmaxf(fmaxf(vm[0], vm[1]), fmaxf(vm[2], vm[3]));
      #pragma unroll
      for (int off = 1; off < 64; off <<= 1)
        tmax = fmaxf(tmax, __shfl_xor(tmax, off));

      if (tmax > m_w + THR_LOG2) {
        const float corr = __builtin_amdgcn_exp2f(m_w - tmax);
        #pragma unroll
        for (int m = 0; m < 2; ++m) {
          #pragma unroll
          for (int c = 0; c < 4; ++c) acc_o[m][c] *= corr;
          acc_l[m] *= corr;
        }
        m_w = tmax;
      }

      float mk[4];
      #pragma unroll
      for (int n = 0; n < 4; ++n)
        mk[n] = (amask[b*T_ + kb*64 + n*16 + l15] != 0) ? m_w : 3e37f;

      #pragma unroll
      for (int m = 0; m < 2; ++m)
        #pragma unroll
        for (int r = 0; r < 4; ++r) {
          const int row = m*16 + lhi*4 + r;
          const int sw = (row & 7) << 4;
          #pragma unroll
          for (int n = 0; n < 4; ++n) {
            const float p = __builtin_amdgcn_exp2f(sc[m][n][r] - mk[n]);
            *(__bf16*)(lPw + row*128 + ((((n*16 + l15)*2)) ^ sw)) = (__bf16)p;
          }
        }

      bf16x8 pa[2][2];
      #pragma unroll
      for (int m = 0; m < 2; ++m) {
        const int row = m*16 + l15;
        const int sw = (row & 7) << 4;
        #pragma unroll
        for (int ks = 0; ks < 2; ++ks)
          pa[m][ks] = *(const bf16x8*)(lPw + row*128 + ((ks*64 + lhi*16) ^ sw));
      }

      __builtin_amdgcn_s_setprio(1);
      const __bf16 one = (__bf16)1.0f;
      const bf16x8 vone = {one, one, one, one, one, one, one, one};
      #pragma unroll
      for (int m = 0; m < 2; ++m)
        #pragma unroll
        for (int ks = 0; ks < 2; ++ks)
          acc_l[m] = mfma_bf16(pa[m][ks], vone, acc_l[m]);

      #pragma unroll
      for (int c = 0; c < 4; ++c) {
        const int row = c*16 + l15;
        const int sw = (row & 7) << 4;
        #pragma unroll
        for (int ks = 0; ks < 2; ++ks) {
          bf16x8 bv = *(const bf16x8*)(lVc + row*128 + ((ks*64 + lhi*16) ^ sw));
          #pragma unroll
          for (int m = 0; m < 2; ++m)
            acc_o[m][c] = mfma_bf16(pa[m][ks], bv, acc_o[m][c]);
        }
      }
      __builtin_amdgcn_s_setprio(0);
    }
    __syncthreads();
  }

  if (sp == 2) {
    // direct: normalize and write
    #pragma unroll
    for (int m = 0; m < 2; ++m)
      #pragma unroll
      for (int r = 0; r < 4; ++r) {
        const int tq = q0w + m*16 + lhi*4 + r;
        const float invl = 1.0f / acc_l[m][r];
        const size_t obase = ((size_t)b*T_ + tq)*C_ + h*D_;
        #pragma unroll
        for (int c = 0; c < 4; ++c)
          aout[obase + c*16 + l15] = (__bf16)(acc_o[m][c][r] * invl);
      }
  } else {
    // partial: unnormalized O (f32) + per-row m, l
    const int pidx = ((qblock - 8)*2 + sp)*64 + bh;
    float* po = pO + (size_t)pidx*128*64;
    float* pm = pM + pidx*128;
    float* pl = pL + pidx*128;
    #pragma unroll
    for (int m = 0; m < 2; ++m)
      #pragma unroll
      for (int r = 0; r < 4; ++r) {
        const int rw = wave*32 + m*16 + lhi*4 + r;
        if (l15 == 0) { pm[rw] = m_w; pl[rw] = acc_l[m][r]; }
        #pragma unroll
        for (int c = 0; c < 4; ++c)
          po[(size_t)rw*64 + c*16 + l15] = acc_o[m][c][r];
      }
  }
}

// merge the two kv-split partials for qblock in [8,16)
__global__ void __launch_bounds__(256)
attn_combine(const float* __restrict__ pO, const float* __restrict__ pM,
             const float* __restrict__ pL, __bf16* __restrict__ aout)
{
  const int g = blockIdx.x;            // 512: qb8*64 + bh
  const int qb8 = g >> 6, bh = g & 63;
  const int p0 = (qb8*2)*64 + bh, p1 = (qb8*2 + 1)*64 + bh;
  const int row = threadIdx.x >> 1, ch = threadIdx.x & 1;
  const float m0 = pM[p0*128 + row], m1 = pM[p1*128 + row];
  const float l0 = pL[p0*128 + row], l1 = pL[p1*128 + row];
  const float M = fmaxf(m0, m1);
  const float w0 = __builtin_amdgcn_exp2f(m0 - M);
  const float w1 = __builtin_amdgcn_exp2f(m1 - M);
  const float inv = 1.0f / (l0*w0 + l1*w1);
  const int b = bh >> 4, h = bh & 15;
  const int t = (qb8 + 8)*128 + row;
  const float* o0 = pO + ((size_t)p0*128 + row)*64 + ch*32;
  const float* o1 = pO + ((size_t)p1*128 + row)*64 + ch*32;
  __bf16* dst = aout + ((size_t)b*T_ + t)*C_ + h*D_ + ch*32;
  #pragma unroll
  for (int j = 0; j < 32; j += 4) {
    float4 a = *(const float4*)(o0 + j);
    float4 c = *(const float4*)(o1 + j);
    bf16x4 rr;
    rr[0] = (__bf16)((a.x*w0 + c.x*w1) * inv);
    rr[1] = (__bf16)((a.y*w0 + c.y*w1) * inv);
    rr[2] = (__bf16)((a.z*w0 + c.z*w1) * inv);
    rr[3] = (__bf16)((a.w*w0 + c.w*w1) * inv);
    *(bf16x4*)(dst + j) = rr;
  }
}

// ---------------- launch ----------------

extern "C" void kernel_launch(void* const* d_in, const int* in_sizes, int n_in,
                              void* d_out, int out_size, void* d_ws, size_t ws_size,
                              hipStream_t stream)
{
  const float* x     = (const float*)d_in[0];
  const int*   amask = (const int*)d_in[1];
  const float* Wqkv  = (const float*)d_in[2];
  const float* Wout  = (const float*)d_in[3];
  const float* bout  = (const float*)d_in[4];
  float* out = (float*)d_out;

  char* w = (char*)d_ws;
  __bf16* xb    = (__bf16*)w;  w += (size_t)M_TOT*C_*2;       // 16 MB (reused as vtb after QKV GEMM)
  __bf16* wqkvT = (__bf16*)w;  w += (size_t)3072*1024*2;      // 6 MB
  __bf16* woutT = (__bf16*)w;  w += (size_t)1024*1024*2;      // 2 MB
  __bf16* qb    = (__bf16*)w;  w += (size_t)B_*H_*T_*D_*2;    // 16 MB
  __bf16* kb    = (__bf16*)w;  w += (size_t)B_*H_*T_*D_*2;    // 16 MB
  __bf16* vb    = (__bf16*)w;  w += (size_t)B_*H_*T_*D_*2;    // 16 MB
  __bf16* aob   = (__bf16*)w;  w += (size_t)M_TOT*C_*2;       // 16 MB
  float*  cosT  = (float*)w;   w += (size_t)T_*32*4;
  float*  sinT  = (float*)w;   w += (size_t)T_*32*4;
  float*  pO    = (float*)w;   w += (size_t)1024*128*64*4;    // 33.5 MB split partials
  float*  pM    = (float*)w;   w += (size_t)1024*128*4;
  float*  pL    = (float*)w;   w += (size_t)1024*128*4;
  __bf16* vtb   = xb;   // xb dead after QKV GEMM; alias for V^T

  f32_to_bf16_k<<<(M_TOT*C_/4 + 255)/256, 256, 0, stream>>>(x, xb, M_TOT*C_/4);
  transpose_to_bf16<<<dim3(96, 32), 256, 0, stream>>>(Wqkv, wqkvT, 1024, 3072);
  transpose_to_bf16<<<dim3(32, 32), 256, 0, stream>>>(Wout, woutT, 1024, 1024);
  rope_tables_k<<<(T_*32)/256, 256, 0, stream>>>(cosT, sinT);

  gemm_qkv_p<<<dim3(768), 512, 0, stream>>>(xb, wqkvT, qb, kb, vb, cosT, sinT);

  vtrans_k<<<dim3(T_/64, B_*H_), 256, 0, stream>>>(vb, vtb);

  attn_kernel<<<dim3(1536), 256, 0, stream>>>(qb, kb, vtb, amask, aob, pO, pM, pL);
  attn_combine<<<dim3(512), 256, 0, stream>>>(pO, pM, pL, aob);

  gemm_out_p<<<dim3(256), 512, 0, stream>>>(aob, woutT, out, bout);
}

// Round 8
// 203.889 us; speedup vs baseline: 1.1389x; 1.0577x over previous
//
#include <hip/hip_runtime.h>
#include <hip/hip_bf16.h>
#include <math.h>

typedef __attribute__((ext_vector_type(8))) __bf16 bf16x8;
typedef __attribute__((ext_vector_type(4))) __bf16 bf16x4;
typedef __attribute__((ext_vector_type(4))) float f32x4;

#define B_ 4
#define T_ 2048
#define C_ 1024
#define H_ 16
#define D_ 64
#define M_TOT (B_*T_)

static __device__ __forceinline__ f32x4 mfma_bf16(bf16x8 a, bf16x8 b, f32x4 c) {
  return __builtin_amdgcn_mfma_f32_16x16x32_bf16(a, b, c, 0, 0, 0);
}

static __device__ __forceinline__ void gload_lds16(const void* g, void* l) {
  __builtin_amdgcn_global_load_lds((const __attribute__((address_space(1))) void*)g,
                                   (__attribute__((address_space(3))) void*)l, 16, 0, 0);
}

// ---------------- converts ----------------

__global__ void f32_to_bf16_k(const float* __restrict__ in, __bf16* __restrict__ out, int n4) {
  int i = blockIdx.x * blockDim.x + threadIdx.x;
  if (i < n4) {
    float4 v = ((const float4*)in)[i];
    bf16x4 o = { (__bf16)v.x, (__bf16)v.y, (__bf16)v.z, (__bf16)v.w };
    *(bf16x4*)(out + (size_t)i*4) = o;
  }
}

// out[n][k] = in[k][n], out bf16 (N x K), in fp32 (K x N)
__global__ void transpose_to_bf16(const float* __restrict__ in, __bf16* __restrict__ out, int K, int N) {
  __shared__ float tile[32][33];
  int n0 = blockIdx.x * 32, k0 = blockIdx.y * 32;
  int tx = threadIdx.x & 31, ty = threadIdx.x >> 5;
  #pragma unroll
  for (int r = ty; r < 32; r += 8) tile[r][tx] = in[(size_t)(k0 + r)*N + n0 + tx];
  __syncthreads();
  #pragma unroll
  for (int r = ty; r < 32; r += 8) out[(size_t)(n0 + r)*K + k0 + tx] = (__bf16)tile[tx][r];
}

__global__ void rope_tables_k(float* __restrict__ cosT, float* __restrict__ sinT) {
  int idx = blockIdx.x * 256 + threadIdx.x;   // T_*32 total
  int t = idx >> 5, d = idx & 31;
  float inv = powf(10000.0f, -((float)(2*d)) / 64.0f);
  float ang = (float)t * inv;
  cosT[idx] = cosf(ang);
  sinT[idx] = sinf(ang);
}

// V [bh][t][d] -> Vt [bh][d][t]
__global__ void __launch_bounds__(256)
vtrans_k(const __bf16* __restrict__ v, __bf16* __restrict__ vt) {
  __shared__ __bf16 tile[64][72];
  const int tid = threadIdx.x;
  const int bh = blockIdx.y;
  const int t0 = blockIdx.x * 64;
  const __bf16* src = v + ((size_t)bh*T_ + t0)*D_;
  #pragma unroll
  for (int c = 0; c < 2; ++c) {
    int idx = tid + c*256;
    int row = idx >> 3, col8 = (idx & 7) * 8;
    *(bf16x8*)&tile[row][col8] = *(const bf16x8*)(src + row*D_ + col8);
  }
  __syncthreads();
  __bf16* dst = vt + (size_t)bh*D_*T_ + t0;
  #pragma unroll
  for (int c = 0; c < 2; ++c) {
    int idx = tid + c*256;
    int d = idx >> 3, t8 = (idx & 7) * 8;
    bf16x8 ov;
    #pragma unroll
    for (int j = 0; j < 8; ++j) ov[j] = tile[t8 + j][d];
    *(bf16x8*)(dst + (size_t)d*T_ + t8) = ov;
  }
}

// ---------------- fine-phase pipelined GEMM: 128x256 tile, BK=64, 8 waves -----------
// Round-8 change: M-BANDED XCD MAPPING. Old swizzle gave each XCD all 64 M-tiles
// (16 MB A working set through 4 MB L2 -> FETCH 108 MB ~= 6x A re-fetch, stage
// loads L2-miss, vmcnt stalls). New: xcd = id&7 owns an 8-row-tile M-band
// (A slice 2 MB, L2-resident) and sweeps N; concurrent 32 blocks/XCD cover
// 8 rows x 4 cols (A 2MB + B 2MB fits L2). Bijective: rowt = xcd*8+(j&7),
// col = j>>3. Schedule/addressing byte-identical to round 7.

#define GEMM_PHASES(N_TILES)                                                     \
  auto RD_BFR = [&](const char* lb, bf16x8 (*bfr)[2]) {                          \
    _Pragma("unroll")                                                            \
    for (int n = 0; n < 4; ++n) {                                                \
      const int row = wc*64 + n*16 + l15;                                        \
      const int sw = (row & 7) << 4;                                             \
      _Pragma("unroll")                                                          \
      for (int ks = 0; ks < 2; ++ks)                                             \
        bfr[n][ks] = *(const bf16x8*)(lb + row*128 + ((ks*64 + lhi*16) ^ sw));   \
    }                                                                            \
  };                                                                             \
  auto RD_AF = [&](const char* la, int mb, bf16x8 (*af)[2]) {                    \
    _Pragma("unroll")                                                            \
    for (int mm = 0; mm < 2; ++mm) {                                             \
      const int row = wr*64 + (mb + mm)*16 + l15;                                \
      const int sw = (row & 7) << 4;                                             \
      _Pragma("unroll")                                                          \
      for (int ks = 0; ks < 2; ++ks)                                             \
        af[mm][ks] = *(const bf16x8*)(la + row*128 + ((ks*64 + lhi*16) ^ sw));   \
    }                                                                            \
  };                                                                             \
  auto MFMA16 = [&](bf16x8 (*af)[2], bf16x8 (*bfr)[2], int mb) {                 \
    __builtin_amdgcn_s_setprio(1);                                               \
    _Pragma("unroll")                                                            \
    for (int mm = 0; mm < 2; ++mm)                                               \
      _Pragma("unroll")                                                          \
      for (int n = 0; n < 4; ++n)                                                \
        _Pragma("unroll")                                                        \
        for (int ks = 0; ks < 2; ++ks)                                           \
          acc[mb + mm][n] = mfma_bf16(af[mm][ks], bfr[n][ks], acc[mb + mm][n]);  \
    __builtin_amdgcn_s_setprio(0);                                               \
  };                                                                             \
  /* prologue: B(0)->lB0, A(0)->lA0, B(1)->lB1; drain B0+A0, keep B1 in flight */\
  STAGE_B(0, (char*)lB[0]); STAGE_A(0, (char*)lA[0]); STAGE_B(1, (char*)lB[1]);  \
  asm volatile("s_waitcnt vmcnt(4)" ::: "memory");                               \
  __builtin_amdgcn_s_barrier();                                                  \
  _Pragma("unroll")                                                              \
  for (int it = 0; it < (N_TILES)/2; ++it) {                                     \
    const int t0 = it*2;                                                         \
    bf16x8 bfr[4][2], af[2][2];                                                  \
    /* P1: tile t0 (buf0), m0,m1; stage A(t0+1)->buf1 */                         \
    RD_BFR((const char*)lB[0], bfr);                                             \
    RD_AF((const char*)lA[0], 0, af);                                            \
    STAGE_A(t0 + 1, (char*)lA[1]);                                               \
    __builtin_amdgcn_s_barrier();                                                \
    MFMA16(af, bfr, 0);                                                          \
    __builtin_amdgcn_s_barrier();                                                \
    /* P2: tile t0, m2,m3; stage B(t0+2)->buf0; vmcnt */                         \
    RD_AF((const char*)lA[0], 2, af);                                            \
    if (t0 + 2 < (N_TILES)) STAGE_B(t0 + 2, (char*)lB[0]);                       \
    __builtin_amdgcn_s_barrier();                                                \
    MFMA16(af, bfr, 2);                                                          \
    if (t0 + 2 < (N_TILES)) asm volatile("s_waitcnt vmcnt(4)" ::: "memory");     \
    else                    asm volatile("s_waitcnt vmcnt(0)" ::: "memory");     \
    __builtin_amdgcn_s_barrier();                                                \
    /* P3: tile t0+1 (buf1), m0,m1; stage A(t0+2)->buf0 */                       \
    RD_BFR((const char*)lB[1], bfr);                                             \
    RD_AF((const char*)lA[1], 0, af);                                            \
    if (t0 + 2 < (N_TILES)) STAGE_A(t0 + 2, (char*)lA[0]);                       \
    __builtin_amdgcn_s_barrier();                                                \
    MFMA16(af, bfr, 0);                                                          \
    __builtin_amdgcn_s_barrier();                                                \
    /* P4: tile t0+1, m2,m3; stage B(t0+3)->buf1; vmcnt */                       \
    RD_AF((const char*)lA[1], 2, af);                                            \
    if (t0 + 3 < (N_TILES)) STAGE_B(t0 + 3, (char*)lB[1]);                       \
    __builtin_amdgcn_s_barrier();                                                \
    MFMA16(af, bfr, 2);                                                          \
    if (it < (N_TILES)/2 - 1) asm volatile("s_waitcnt vmcnt(4)" ::: "memory");   \
    __builtin_amdgcn_s_barrier();                                                \
  }

__global__ void __launch_bounds__(512, 2)
gemm_qkv_p(const __bf16* __restrict__ A, const __bf16* __restrict__ Bt,
           __bf16* __restrict__ qout, __bf16* __restrict__ kout, __bf16* __restrict__ vout,
           const float* __restrict__ cosT, const float* __restrict__ sinT)
{
  __shared__ __attribute__((aligned(16))) __bf16 lA[2][128*64];   // 32 KB
  __shared__ __attribute__((aligned(16))) __bf16 lB[2][256*64];   // 64 KB
  const int tid = threadIdx.x;
  const int lane = tid & 63, wave = tid >> 6;
  const int wr = wave >> 2, wc = wave & 3;       // 2M x 4N wave grid
  const int l15 = lane & 15, lhi = lane >> 4;

  // M-banded XCD mapping: xcd owns 8 contiguous M-tiles, sweeps N
  const int id = blockIdx.x;                 // 768 blocks
  const int xcd = id & 7, j = id >> 3;       // j in [0,96)
  const int rowt = xcd*8 + (j & 7);          // [0,64)
  const int row0 = rowt * 128;
  const int col0 = (j >> 3) * 256;           // [0,12) * 256

  f32x4 acc[4][4] = {};

  const char* Abase = (const char*)A + (size_t)row0 * 2048;   // K=1024, 2048 B/row
  const char* Bbase = (const char*)Bt + (size_t)col0 * 2048;

  auto STAGE_A = [&](int kt, char* dst) {
    #pragma unroll
    for (int c = 0; c < 2; ++c) {            // A: 128 rows x 128 B = 16 KB
      const int L = tid*16 + c*8192;
      const int row = L >> 7, colb = L & 127;
      const int sb = colb ^ ((row & 7) << 4);   // inverse swizzle on global source
      gload_lds16(Abase + (size_t)row*2048 + kt*128 + sb, dst + L);
    }
  };
  auto STAGE_B = [&](int kt, char* dst) {
    #pragma unroll
    for (int c = 0; c < 4; ++c) {            // B: 256 rows x 128 B = 32 KB
      const int L = tid*16 + c*8192;
      const int row = L >> 7, colb = L & 127;
      const int sb = colb ^ ((row & 7) << 4);
      gload_lds16(Bbase + (size_t)row*2048 + kt*128 + sb, dst + L);
    }
  };

  GEMM_PHASES(16)

  // epilogue: RoPE on q,k; scatter to (B,H,T,D); q pre-scaled by 0.125*log2e
  const int slot = (col0 >> 6) + wc;         // 0..47
  const int which = slot >> 4;               // 0=q 1=k 2=v
  const int h = slot & 15;
  const float fsc = (which == 0) ? 0.18033688011112042f : 1.0f;
  #pragma unroll
  for (int m = 0; m < 4; ++m) {
    #pragma unroll
    for (int r = 0; r < 4; ++r) {
      const int grow = row0 + wr*64 + m*16 + lhi*4 + r;
      const int b = grow >> 11, t = grow & 2047;
      const size_t obase = ((size_t)(b*H_ + h)*T_ + t)*D_;
      if (which == 2) {
        #pragma unroll
        for (int n = 0; n < 4; ++n)
          vout[obase + n*16 + l15] = (__bf16)acc[m][n][r];
      } else {
        __bf16* dst = (which == 0) ? qout : kout;
        #pragma unroll
        for (int n = 0; n < 2; ++n) {
          const int d1 = n*16 + l15;            // [0,32)
          const float c = cosT[t*32 + d1];
          const float s = sinT[t*32 + d1];
          const float x1 = acc[m][n][r];
          const float x2 = acc[m][n+2][r];
          dst[obase + d1]      = (__bf16)((x1*c - x2*s) * fsc);
          dst[obase + d1 + 32] = (__bf16)((x1*s + x2*c) * fsc);
        }
      }
    }
  }
}

// out-proj: same fine-phase structure + M-banded XCD mapping. Grid 256 = 1 round.
__global__ void __launch_bounds__(512, 2)
gemm_out_p(const __bf16* __restrict__ A, const __bf16* __restrict__ Bt,
           float* __restrict__ fout, const float* __restrict__ bias)
{
  __shared__ __attribute__((aligned(16))) __bf16 lA[2][128*64];
  __shared__ __attribute__((aligned(16))) __bf16 lB[2][256*64];
  const int tid = threadIdx.x;
  const int lane = tid & 63, wave = tid >> 6;
  const int wr = wave >> 2, wc = wave & 3;
  const int l15 = lane & 15, lhi = lane >> 4;

  const int id = blockIdx.x;                 // 256 blocks
  const int xcd = id & 7, j = id >> 3;       // j in [0,32)
  const int rowt = xcd*8 + (j & 7);          // [0,64)
  const int row0 = rowt * 128;
  const int col0 = (j >> 3) * 256;           // [0,4) * 256

  f32x4 acc[4][4] = {};

  const char* Abase = (const char*)A + (size_t)row0 * 2048;
  const char* Bbase = (const char*)Bt + (size_t)col0 * 2048;

  auto STAGE_A = [&](int kt, char* dst) {
    #pragma unroll
    for (int c = 0; c < 2; ++c) {
      const int L = tid*16 + c*8192;
      const int row = L >> 7, colb = L & 127;
      const int sb = colb ^ ((row & 7) << 4);
      gload_lds16(Abase + (size_t)row*2048 + kt*128 + sb, dst + L);
    }
  };
  auto STAGE_B = [&](int kt, char* dst) {
    #pragma unroll
    for (int c = 0; c < 4; ++c) {
      const int L = tid*16 + c*8192;
      const int row = L >> 7, colb = L & 127;
      const int sb = colb ^ ((row & 7) << 4);
      gload_lds16(Bbase + (size_t)row*2048 + kt*128 + sb, dst + L);
    }
  };

  GEMM_PHASES(16)

  #pragma unroll
  for (int m = 0; m < 4; ++m) {
    #pragma unroll
    for (int r = 0; r < 4; ++r) {
      const int grow = row0 + wr*64 + m*16 + lhi*4 + r;
      #pragma unroll
      for (int n = 0; n < 4; ++n) {
        const int gcol = col0 + wc*64 + n*16 + l15;
        fout[(size_t)grow*1024 + gcol] = acc[m][n][r] + bias[gcol];
      }
    }
  }
}

// ---------------- flash attention: split-KV + LPT, Q-in-LDS, 3 blocks/CU ----------
#define THR_LOG2 8.0f

// group (blockIdx>>6) -> qblock, split (0/1 = kv half, 2 = direct full range)
static __device__ const char QB_TAB[24] = {15,15,7,14,14,13,13,6,12,12,11,11,5,10,10,9,9,4,8,8,3,2,1,0};
static __device__ const char SP_TAB[24] = { 0, 1,2, 0, 1, 0, 1,2, 0, 1, 0, 1,2, 0, 1,0,1,2,0,1,2,2,2,2};

__global__ void __launch_bounds__(256, 3)
attn_kernel(const __bf16* __restrict__ q, const __bf16* __restrict__ k,
            const __bf16* __restrict__ vt, const int* __restrict__ amask,
            __bf16* __restrict__ aout,
            float* __restrict__ pO, float* __restrict__ pM, float* __restrict__ pL)
{
  __shared__ __attribute__((aligned(16))) __bf16 lK[64*64];    // 8 KB
  __shared__ __attribute__((aligned(16))) __bf16 lVt[64*64];   // 8 KB
  __shared__ __attribute__((aligned(16))) __bf16 lP[4][32*64]; // 16 KB
  __shared__ __attribute__((aligned(16))) __bf16 lQ[128*64];   // 16 KB
  const int tid = threadIdx.x;
  const int lane = tid & 63, wave = tid >> 6;
  const int l15 = lane & 15, lhi = lane >> 4;

  const int g = blockIdx.x >> 6;
  const int bh = blockIdx.x & 63;
  const int qblock = QB_TAB[g];
  const int sp = SP_TAB[g];
  const int kb0   = (sp == 1) ? (qblock + 1) : 0;
  const int kbend = (sp == 0) ? (qblock + 1) : (2*qblock + 2);

  const int b = bh >> 4, h = bh & 15;
  const size_t kvbase = (size_t)bh * T_ * D_;
  const char* kbase  = (const char*)(k + kvbase);
  const char* vtbase = (const char*)(vt + kvbase);
  char* lPw = (char*)lP[wave];

  const int q0w = qblock*128 + wave*32;

  // stage Q tile (128 rows x 128B) once; swizzled like lK
  {
    const char* qgbase = (const char*)(q + kvbase) + (size_t)qblock*128*128;
    #pragma unroll
    for (int c = 0; c < 4; ++c) {
      const int L = tid*16 + c*4096;
      const int row = L >> 7;
      const int sb = (L & 127) ^ ((row & 7) << 4);
      gload_lds16(qgbase + (size_t)row*128 + sb, (char*)lQ + L);
    }
  }

  f32x4 acc_o[2][4] = {};
  f32x4 acc_l[2] = {};
  float m_w = -3e37f;

  for (int kb = kb0; kb < kbend; ++kb) {
    #pragma unroll
    for (int c = 0; c < 2; ++c) {
      const int L = tid*16 + c*4096;
      const int row = L >> 7;
      const int sb  = (L & 127) ^ ((row & 7) << 4);
      gload_lds16(kbase  + (size_t)(kb*64 + row)*128 + sb, (char*)lK + L);
      gload_lds16(vtbase + (size_t)row*(T_*2) + (size_t)kb*128 + sb, (char*)lVt + L);
    }
    __syncthreads();

    if (kb*64 <= q0w + 31) {
      const char* lKc = (const char*)lK;
      const char* lVc = (const char*)lVt;
      const char* lQw = (const char*)lQ + (wave*32)*128;
      asm volatile("" : "+v"(lQw));   // defeat cross-iteration hoist of Q reads

      // Q fragments from LDS (re-read each iteration -> not loop-carried regs)
      bf16x8 aq[2][2];
      #pragma unroll
      for (int m = 0; m < 2; ++m) {
        const int lr = m*16 + l15;
        const int sw = (lr & 7) << 4;
        #pragma unroll
        for (int ks = 0; ks < 2; ++ks)
          aq[m][ks] = *(const bf16x8*)(lQw + lr*128 + ((ks*64 + lhi*16) ^ sw));
      }

      f32x4 sc[2][4] = {};
      __builtin_amdgcn_s_setprio(1);
      #pragma unroll
      for (int n = 0; n < 4; ++n) {
        const int row = n*16 + l15;
        const int sw = (row & 7) << 4;
        #pragma unroll
        for (int ks = 0; ks < 2; ++ks) {
          bf16x8 bk = *(const bf16x8*)(lKc + row*128 + ((ks*64 + lhi*16) ^ sw));
          #pragma unroll
          for (int m = 0; m < 2; ++m)
            sc[m][n] = mfma_bf16(aq[m][ks], bk, sc[m][n]);
        }
      }
      __builtin_amdgcn_s_setprio(0);

      if (kb*64 + 63 > q0w) {
        #pragma unroll
        for (int m = 0; m < 2; ++m)
          #pragma unroll
          for (int r = 0; r < 4; ++r) {
            const int tq = q0w + m*16 + lhi*4 + r;
            #pragma unroll
            for (int n = 0; n < 4; ++n)
              if (kb*64 + n*16 + l15 > tq) sc[m][n][r] = -3e37f;
          }
      }

      f32x4 vm = sc[0][0];
      #pragma unroll
      for (int m = 0; m < 2; ++m)
        #pragma unroll
        for (int n = 0; n < 4; ++n) {
          if (m == 0 && n == 0) continue;
          #pragma unroll
          for (int r = 0; r < 4; ++r) vm[r] = fmaxf(vm[r], sc[m][n][r]);
        }
      float tmax = fmaxf(fmaxf(vm[0], vm[1]), fmaxf(vm[2], vm[3]));
      #pragma unroll
      for (int off = 1; off < 64; off <<= 1)
        tmax = fmaxf(tmax, __shfl_xor(tmax, off));

      if (tmax > m_w + THR_LOG2) {
        const float corr = __builtin_amdgcn_exp2f(m_w - tmax);
        #pragma unroll
        for (int m = 0; m < 2; ++m) {
          #pragma unroll
          for (int c = 0; c < 4; ++c) acc_o[m][c] *= corr;
          acc_l[m] *= corr;
        }
        m_w = tmax;
      }

      float mk[4];
      #pragma unroll
      for (int n = 0; n < 4; ++n)
        mk[n] = (amask[b*T_ + kb*64 + n*16 + l15] != 0) ? m_w : 3e37f;

      #pragma unroll
      for (int m = 0; m < 2; ++m)
        #pragma unroll
        for (int r = 0; r < 4; ++r) {
          const int row = m*16 + lhi*4 + r;
          const int sw = (row & 7) << 4;
          #pragma unroll
          for (int n = 0; n < 4; ++n) {
            const float p = __builtin_amdgcn_exp2f(sc[m][n][r] - mk[n]);
            *(__bf16*)(lPw + row*128 + ((((n*16 + l15)*2)) ^ sw)) = (__bf16)p;
          }
        }

      bf16x8 pa[2][2];
      #pragma unroll
      for (int m = 0; m < 2; ++m) {
        const int row = m*16 + l15;
        const int sw = (row & 7) << 4;
        #pragma unroll
        for (int ks = 0; ks < 2; ++ks)
          pa[m][ks] = *(const bf16x8*)(lPw + row*128 + ((ks*64 + lhi*16) ^ sw));
      }

      __builtin_amdgcn_s_setprio(1);
      const __bf16 one = (__bf16)1.0f;
      const bf16x8 vone = {one, one, one, one, one, one, one, one};
      #pragma unroll
      for (int m = 0; m < 2; ++m)
        #pragma unroll
        for (int ks = 0; ks < 2; ++ks)
          acc_l[m] = mfma_bf16(pa[m][ks], vone, acc_l[m]);

      #pragma unroll
      for (int c = 0; c < 4; ++c) {
        const int row = c*16 + l15;
        const int sw = (row & 7) << 4;
        #pragma unroll
        for (int ks = 0; ks < 2; ++ks) {
          bf16x8 bv = *(const bf16x8*)(lVc + row*128 + ((ks*64 + lhi*16) ^ sw));
          #pragma unroll
          for (int m = 0; m < 2; ++m)
            acc_o[m][c] = mfma_bf16(pa[m][ks], bv, acc_o[m][c]);
        }
      }
      __builtin_amdgcn_s_setprio(0);
    }
    __syncthreads();
  }

  if (sp == 2) {
    // direct: normalize and write
    #pragma unroll
    for (int m = 0; m < 2; ++m)
      #pragma unroll
      for (int r = 0; r < 4; ++r) {
        const int tq = q0w + m*16 + lhi*4 + r;
        const float invl = 1.0f / acc_l[m][r];
        const size_t obase = ((size_t)b*T_ + tq)*C_ + h*D_;
        #pragma unroll
        for (int c = 0; c < 4; ++c)
          aout[obase + c*16 + l15] = (__bf16)(acc_o[m][c][r] * invl);
      }
  } else {
    // partial: unnormalized O (f32) + per-row m, l
    const int pidx = ((qblock - 8)*2 + sp)*64 + bh;
    float* po = pO + (size_t)pidx*128*64;
    float* pm = pM + pidx*128;
    float* pl = pL + pidx*128;
    #pragma unroll
    for (int m = 0; m < 2; ++m)
      #pragma unroll
      for (int r = 0; r < 4; ++r) {
        const int rw = wave*32 + m*16 + lhi*4 + r;
        if (l15 == 0) { pm[rw] = m_w; pl[rw] = acc_l[m][r]; }
        #pragma unroll
        for (int c = 0; c < 4; ++c)
          po[(size_t)rw*64 + c*16 + l15] = acc_o[m][c][r];
      }
  }
}

// merge the two kv-split partials for qblock in [8,16)
__global__ void __launch_bounds__(256)
attn_combine(const float* __restrict__ pO, const float* __restrict__ pM,
             const float* __restrict__ pL, __bf16* __restrict__ aout)
{
  const int g = blockIdx.x;            // 512: qb8*64 + bh
  const int qb8 = g >> 6, bh = g & 63;
  const int p0 = (qb8*2)*64 + bh, p1 = (qb8*2 + 1)*64 + bh;
  const int row = threadIdx.x >> 1, ch = threadIdx.x & 1;
  const float m0 = pM[p0*128 + row], m1 = pM[p1*128 + row];
  const float l0 = pL[p0*128 + row], l1 = pL[p1*128 + row];
  const float M = fmaxf(m0, m1);
  const float w0 = __builtin_amdgcn_exp2f(m0 - M);
  const float w1 = __builtin_amdgcn_exp2f(m1 - M);
  const float inv = 1.0f / (l0*w0 + l1*w1);
  const int b = bh >> 4, h = bh & 15;
  const int t = (qb8 + 8)*128 + row;
  const float* o0 = pO + ((size_t)p0*128 + row)*64 + ch*32;
  const float* o1 = pO + ((size_t)p1*128 + row)*64 + ch*32;
  __bf16* dst = aout + ((size_t)b*T_ + t)*C_ + h*D_ + ch*32;
  #pragma unroll
  for (int j = 0; j < 32; j += 4) {
    float4 a = *(const float4*)(o0 + j);
    float4 c = *(const float4*)(o1 + j);
    bf16x4 rr;
    rr[0] = (__bf16)((a.x*w0 + c.x*w1) * inv);
    rr[1] = (__bf16)((a.y*w0 + c.y*w1) * inv);
    rr[2] = (__bf16)((a.z*w0 + c.z*w1) * inv);
    rr[3] = (__bf16)((a.w*w0 + c.w*w1) * inv);
    *(bf16x4*)(dst + j) = rr;
  }
}

// ---------------- launch ----------------

extern "C" void kernel_launch(void* const* d_in, const int* in_sizes, int n_in,
                              void* d_out, int out_size, void* d_ws, size_t ws_size,
                              hipStream_t stream)
{
  const float* x     = (const float*)d_in[0];
  const int*   amask = (const int*)d_in[1];
  const float* Wqkv  = (const float*)d_in[2];
  const float* Wout  = (const float*)d_in[3];
  const float* bout  = (const float*)d_in[4];
  float* out = (float*)d_out;

  char* w = (char*)d_ws;
  __bf16* xb    = (__bf16*)w;  w += (size_t)M_TOT*C_*2;       // 16 MB (reused as vtb after QKV GEMM)
  __bf16* wqkvT = (__bf16*)w;  w += (size_t)3072*1024*2;      // 6 MB
  __bf16* woutT = (__bf16*)w;  w += (size_t)1024*1024*2;      // 2 MB
  __bf16* qb    = (__bf16*)w;  w += (size_t)B_*H_*T_*D_*2;    // 16 MB
  __bf16* kb    = (__bf16*)w;  w += (size_t)B_*H_*T_*D_*2;    // 16 MB
  __bf16* vb    = (__bf16*)w;  w += (size_t)B_*H_*T_*D_*2;    // 16 MB
  __bf16* aob   = (__bf16*)w;  w += (size_t)M_TOT*C_*2;       // 16 MB
  float*  cosT  = (float*)w;   w += (size_t)T_*32*4;
  float*  sinT  = (float*)w;   w += (size_t)T_*32*4;
  float*  pO    = (float*)w;   w += (size_t)1024*128*64*4;    // 33.5 MB split partials
  float*  pM    = (float*)w;   w += (size_t)1024*128*4;
  float*  pL    = (float*)w;   w += (size_t)1024*128*4;
  __bf16* vtb   = xb;   // xb dead after QKV GEMM; alias for V^T

  f32_to_bf16_k<<<(M_TOT*C_/4 + 255)/256, 256, 0, stream>>>(x, xb, M_TOT*C_/4);
  transpose_to_bf16<<<dim3(96, 32), 256, 0, stream>>>(Wqkv, wqkvT, 1024, 3072);
  transpose_to_bf16<<<dim3(32, 32), 256, 0, stream>>>(Wout, woutT, 1024, 1024);
  rope_tables_k<<<(T_*32)/256, 256, 0, stream>>>(cosT, sinT);

  gemm_qkv_p<<<dim3(768), 512, 0, stream>>>(xb, wqkvT, qb, kb, vb, cosT, sinT);

  vtrans_k<<<dim3(T_/64, B_*H_), 256, 0, stream>>>(vb, vtb);

  attn_kernel<<<dim3(1536), 256, 0, stream>>>(qb, kb, vtb, amask, aob, pO, pM, pL);
  attn_combine<<<dim3(512), 256, 0, stream>>>(pO, pM, pL, aob);

  gemm_out_p<<<dim3(256), 512, 0, stream>>>(aob, woutT, out, bout);
}